// Round 1
// baseline (2927.795 us; speedup 1.0000x reference)
//
#include <hip/hip_runtime.h>

#define ALPHA 0.2f

__device__ __forceinline__ float leakyf(float x) { return x > 0.0f ? x : ALPHA * x; }

// monotone float->uint key: order-preserving, key 0 == "empty" (never produced by finite floats)
__device__ __forceinline__ unsigned fkey(float f) {
    unsigned u = __float_as_uint(f);
    return (u & 0x80000000u) ? ~u : (u | 0x80000000u);
}
__device__ __forceinline__ float funkey(unsigned k) {
    unsigned u = (k & 0x80000000u) ? (k & 0x7FFFFFFFu) : ~k;
    return __uint_as_float(u);
}

// ---------------- fused 3-matrix linear: o_m = x @ W_m + b_m ----------------
// x: [N,128], W: [128,128], o: [N,128]. 32 rows/block, 256 thr, 4x4 micro-tile.
__global__ __launch_bounds__(256) void lin3_kernel(
    const float* __restrict__ x, int N,
    const float* __restrict__ W0, const float* __restrict__ b0, float* __restrict__ o0,
    const float* __restrict__ W1, const float* __restrict__ b1, float* __restrict__ o1,
    const float* __restrict__ W2, const float* __restrict__ b2, float* __restrict__ o2)
{
    __shared__ float xs[32 * 128];
    const int row0 = blockIdx.x * 32;
    // stage 32 rows of x into LDS (guarded via clamp; stores are guarded below)
    {
        float4* xl = (float4*)xs;
        #pragma unroll
        for (int ii = 0; ii < 4; ++ii) {
            int i = threadIdx.x + 256 * ii;          // i in [0,1024): float4 index
            int r = i >> 5;                          // row within tile
            int srcrow = row0 + r;
            if (srcrow >= N) srcrow = N - 1;
            xl[i] = ((const float4*)x)[(size_t)srcrow * 32 + (i & 31)];
        }
    }
    __syncthreads();
    const int c  = threadIdx.x & 31;        // col base (cols c, c+32, c+64, c+96)
    const int r0 = (threadIdx.x >> 5) << 2; // row base (4 rows per thread)

    const float* Wm[3] = {W0, W1, W2};
    const float* bm[3] = {b0, b1, b2};
    float*       om[3] = {o0, o1, o2};
    #pragma unroll
    for (int m = 0; m < 3; ++m) {
        const float* __restrict__ W = Wm[m];
        float acc[4][4] = {};
        #pragma unroll 4
        for (int k = 0; k < 128; ++k) {
            float w[4];
            #pragma unroll
            for (int q = 0; q < 4; ++q) w[q] = W[k * 128 + c + 32 * q];
            #pragma unroll
            for (int r = 0; r < 4; ++r) {
                float xv = xs[(r0 + r) * 128 + k];
                #pragma unroll
                for (int q = 0; q < 4; ++q) acc[r][q] += xv * w[q];
            }
        }
        float bb[4];
        #pragma unroll
        for (int q = 0; q < 4; ++q) bb[q] = bm[m][c + 32 * q];
        #pragma unroll
        for (int r = 0; r < 4; ++r) {
            int row = row0 + r0 + r;
            if (row < N) {
                float* orow = om[m] + (size_t)row * 128;
                #pragma unroll
                for (int q = 0; q < 4; ++q) orow[c + 32 * q] = acc[r][q] + bb[q];
            }
        }
    }
}

// ---------------- per-node attention dots: o[n,h] = dot(Wh[n,h,:], att[h,:]) ----------------
__global__ __launch_bounds__(256) void dot2_kernel(
    const float* __restrict__ Wh, int N4,
    const float* __restrict__ attA, float* __restrict__ oA,
    const float* __restrict__ attB, float* __restrict__ oB)
{
    int gid = blockIdx.x * 256 + threadIdx.x;
    if (gid >= N4) return;
    int h = gid & 3;
    const float4* p  = (const float4*)(Wh + (size_t)gid * 32);
    const float4* a4 = (const float4*)(attA + h * 32);
    float sA = 0.f, sB = 0.f;
    if (oB) {
        const float4* b4 = (const float4*)(attB + h * 32);
        #pragma unroll
        for (int j = 0; j < 8; ++j) {
            float4 v = p[j]; float4 a = a4[j]; float4 b = b4[j];
            sA += v.x * a.x + v.y * a.y + v.z * a.z + v.w * a.w;
            sB += v.x * b.x + v.y * b.y + v.z * b.z + v.w * b.w;
        }
        oA[gid] = sA; oB[gid] = sB;
    } else {
        #pragma unroll
        for (int j = 0; j < 8; ++j) {
            float4 v = p[j]; float4 a = a4[j];
            sA += v.x * a.x + v.y * a.y + v.z * a.z + v.w * a.w;
        }
        oA[gid] = sA;
    }
}

// ---------------- zero fill (graph-capture-safe memset) ----------------
__global__ __launch_bounds__(256) void zero_kernel(float4* __restrict__ p, int n) {
    int i = blockIdx.x * 256 + threadIdx.x;
    if (i < n) p[i] = float4{0.f, 0.f, 0.f, 0.f};
}

// ---------------- edge pass 1: segment max (keyed atomicMax) ----------------
__global__ __launch_bounds__(256) void edge_max_kernel(
    const int* __restrict__ src, const int* __restrict__ dst,
    const float* __restrict__ es, const float* __restrict__ ed,
    unsigned* __restrict__ mkey, int E)
{
    int i = blockIdx.x * 256 + threadIdx.x;
    if (i >= E) return;
    int s = src[i], d = dst[i];
    float4 a = *(const float4*)(es + (size_t)s * 4);
    float4 b = *(const float4*)(ed + (size_t)d * 4);
    unsigned* mp = mkey + (size_t)d * 4;
    atomicMax(mp + 0, fkey(leakyf(a.x + b.x)));
    atomicMax(mp + 1, fkey(leakyf(a.y + b.y)));
    atomicMax(mp + 2, fkey(leakyf(a.z + b.z)));
    atomicMax(mp + 3, fkey(leakyf(a.w + b.w)));
}

// ---------------- edge pass 2: segment sum of exp(e - m) ----------------
__global__ __launch_bounds__(256) void edge_sum_kernel(
    const int* __restrict__ src, const int* __restrict__ dst,
    const float* __restrict__ es, const float* __restrict__ ed,
    const unsigned* __restrict__ mkey, float* __restrict__ ssum, int E)
{
    int i = blockIdx.x * 256 + threadIdx.x;
    if (i >= E) return;
    int s = src[i], d = dst[i];
    float4 a = *(const float4*)(es + (size_t)s * 4);
    float4 b = *(const float4*)(ed + (size_t)d * 4);
    uint4 mk = *(const uint4*)(mkey + (size_t)d * 4);
    float* sp = ssum + (size_t)d * 4;
    atomicAdd(sp + 0, __expf(leakyf(a.x + b.x) - funkey(mk.x)));
    atomicAdd(sp + 1, __expf(leakyf(a.y + b.y) - funkey(mk.y)));
    atomicAdd(sp + 2, __expf(leakyf(a.z + b.z) - funkey(mk.z)));
    atomicAdd(sp + 3, __expf(leakyf(a.w + b.w) - funkey(mk.w)));
}

// ---------------- edge pass 3: out[dst] += Whsrc[src] * a  (one wave per edge) ----------------
__global__ __launch_bounds__(256) void edge_aggr_kernel(
    const int* __restrict__ src, const int* __restrict__ dst,
    const float* __restrict__ es, const float* __restrict__ ed,
    const unsigned* __restrict__ mkey, const float* __restrict__ ssum,
    const float* __restrict__ Whsrc, float* __restrict__ out, int E)
{
    int gid = blockIdx.x * 256 + threadIdx.x;
    int e = gid >> 6;
    if (e >= E) return;
    int lane = gid & 63;
    int s = src[e], d = dst[e];
    int h = lane >> 4;                      // element pair (2*lane, 2*lane+1) -> head
    float eh = leakyf(es[(size_t)s * 4 + h] + ed[(size_t)d * 4 + h]);
    float ah = __expf(eh - funkey(mkey[(size_t)d * 4 + h])) / ssum[(size_t)d * 4 + h];
    float2 w = *(const float2*)(Whsrc + (size_t)s * 128 + lane * 2);
    float* op = out + (size_t)d * 128 + lane * 2;
    atomicAdd(op + 0, w.x * ah);
    atomicAdd(op + 1, w.y * ah);
}

// ---------------- final ReLU ----------------
__global__ __launch_bounds__(256) void relu_kernel(float4* __restrict__ out, int n4) {
    int i = blockIdx.x * 256 + threadIdx.x;
    if (i >= n4) return;
    float4 v = out[i];
    v.x = fmaxf(v.x, 0.f); v.y = fmaxf(v.y, 0.f);
    v.z = fmaxf(v.z, 0.f); v.w = fmaxf(v.w, 0.f);
    out[i] = v;
}

extern "C" void kernel_launch(void* const* d_in, const int* in_sizes, int n_in,
                              void* d_out, int out_size, void* d_ws, size_t ws_size,
                              hipStream_t stream)
{
    const float* feat_P = (const float*)d_in[0];
    const float* feat_A = (const float*)d_in[1];
    const int* src_p2p = (const int*)d_in[2];
    const int* dst_p2p = (const int*)d_in[3];
    const int* src_p2a = (const int*)d_in[4];
    const int* dst_p2a = (const int*)d_in[5];
    const int* src_a2p = (const int*)d_in[6];
    const int* dst_a2p = (const int*)d_in[7];
    const int* src_a2a = (const int*)d_in[8];
    const int* dst_a2a = (const int*)d_in[9];
    const float* W_P   = (const float*)d_in[10]; const float* b_P   = (const float*)d_in[11];
    const float* W_A   = (const float*)d_in[12]; const float* b_A   = (const float*)d_in[13];
    const float* W_p2p = (const float*)d_in[14]; const float* b_p2p = (const float*)d_in[15];
    const float* W_p2a = (const float*)d_in[16]; const float* b_p2a = (const float*)d_in[17];
    const float* W_a2p = (const float*)d_in[18]; const float* b_a2p = (const float*)d_in[19];
    const float* W_a2a = (const float*)d_in[20]; const float* b_a2a = (const float*)d_in[21];
    const float* att_p2p_src = (const float*)d_in[22];
    const float* att_p2p_dst = (const float*)d_in[23];
    const float* att_p2a_src = (const float*)d_in[24];
    const float* att_p2a_dst = (const float*)d_in[25];
    const float* att_a2p_src = (const float*)d_in[26];
    const float* att_a2p_dst = (const float*)d_in[27];
    const float* att_a2a_src = (const float*)d_in[28];
    const float* att_a2a_dst = (const float*)d_in[29];

    const int NP = in_sizes[0] / 128;
    const int NA = in_sizes[1] / 128;
    const int E  = in_sizes[2];

    float* outP = (float*)d_out;
    float* outA = (float*)d_out + (size_t)NP * 128;

    // ---- workspace layout (256B-aligned chunks) ----
    char* ws = (char*)d_ws;
    size_t off = 0;
    auto alloc = [&](size_t bytes) -> void* {
        void* p = ws + off;
        off += (bytes + 255) & ~(size_t)255;
        return p;
    };
    float* Whp2p = (float*)alloc((size_t)NP * 128 * 4);
    float* Whp2a = (float*)alloc((size_t)NP * 128 * 4);
    float* Wha2p = (float*)alloc((size_t)NA * 128 * 4);
    float* Wha2a = (float*)alloc((size_t)NA * 128 * 4);
    float* es_p2p = (float*)alloc((size_t)NP * 16);
    float* ed_p2p = (float*)alloc((size_t)NP * 16);
    float* es_p2a = (float*)alloc((size_t)NP * 16);
    float* ed_p2a = (float*)alloc((size_t)NA * 16);
    float* es_a2p = (float*)alloc((size_t)NA * 16);
    float* ed_a2p = (float*)alloc((size_t)NP * 16);
    float* es_a2a = (float*)alloc((size_t)NA * 16);
    float* ed_a2a = (float*)alloc((size_t)NA * 16);
    size_t ms_begin = off;
    unsigned* m_p2p = (unsigned*)alloc((size_t)NP * 16);  // dst of p2p is P
    float*    s_p2p = (float*)   alloc((size_t)NP * 16);
    unsigned* m_p2a = (unsigned*)alloc((size_t)NA * 16);
    float*    s_p2a = (float*)   alloc((size_t)NA * 16);
    unsigned* m_a2p = (unsigned*)alloc((size_t)NP * 16);
    float*    s_a2p = (float*)   alloc((size_t)NP * 16);
    unsigned* m_a2a = (unsigned*)alloc((size_t)NA * 16);
    float*    s_a2a = (float*)   alloc((size_t)NA * 16);
    size_t ms_bytes = off - ms_begin;

    // ---- 1) fused linears (Whp/Wha go straight into d_out) ----
    lin3_kernel<<<(NP + 31) / 32, 256, 0, stream>>>(feat_P, NP,
        W_P, b_P, outP,  W_p2p, b_p2p, Whp2p,  W_p2a, b_p2a, Whp2a);
    lin3_kernel<<<(NA + 31) / 32, 256, 0, stream>>>(feat_A, NA,
        W_A, b_A, outA,  W_a2p, b_a2p, Wha2p,  W_a2a, b_a2a, Wha2a);

    // ---- 2) zero m/s scratch ----
    {
        int n4 = (int)(ms_bytes / 16);
        zero_kernel<<<(n4 + 255) / 256, 256, 0, stream>>>((float4*)(ws + ms_begin), n4);
    }

    // ---- 3) attention dots ----
    int g4p = (NP * 4 + 255) / 256;
    int g4a = (NA * 4 + 255) / 256;
    dot2_kernel<<<g4p, 256, 0, stream>>>(outP,  NP * 4, att_p2p_dst, ed_p2p, att_a2p_dst, ed_a2p);
    dot2_kernel<<<g4a, 256, 0, stream>>>(outA,  NA * 4, att_p2a_dst, ed_p2a, att_a2a_dst, ed_a2a);
    dot2_kernel<<<g4p, 256, 0, stream>>>(Whp2p, NP * 4, att_p2p_src, es_p2p, nullptr, nullptr);
    dot2_kernel<<<g4p, 256, 0, stream>>>(Whp2a, NP * 4, att_p2a_src, es_p2a, nullptr, nullptr);
    dot2_kernel<<<g4a, 256, 0, stream>>>(Wha2p, NA * 4, att_a2p_src, es_a2p, nullptr, nullptr);
    dot2_kernel<<<g4a, 256, 0, stream>>>(Wha2a, NA * 4, att_a2a_src, es_a2a, nullptr, nullptr);

    // ---- 4) edge softmax: max, sum ----
    int ge = (E + 255) / 256;
    edge_max_kernel<<<ge, 256, 0, stream>>>(src_p2p, dst_p2p, es_p2p, ed_p2p, m_p2p, E);
    edge_max_kernel<<<ge, 256, 0, stream>>>(src_p2a, dst_p2a, es_p2a, ed_p2a, m_p2a, E);
    edge_max_kernel<<<ge, 256, 0, stream>>>(src_a2p, dst_a2p, es_a2p, ed_a2p, m_a2p, E);
    edge_max_kernel<<<ge, 256, 0, stream>>>(src_a2a, dst_a2a, es_a2a, ed_a2a, m_a2a, E);
    edge_sum_kernel<<<ge, 256, 0, stream>>>(src_p2p, dst_p2p, es_p2p, ed_p2p, m_p2p, s_p2p, E);
    edge_sum_kernel<<<ge, 256, 0, stream>>>(src_p2a, dst_p2a, es_p2a, ed_p2a, m_p2a, s_p2a, E);
    edge_sum_kernel<<<ge, 256, 0, stream>>>(src_a2p, dst_a2p, es_a2p, ed_a2p, m_a2p, s_a2p, E);
    edge_sum_kernel<<<ge, 256, 0, stream>>>(src_a2a, dst_a2a, es_a2a, ed_a2a, m_a2a, s_a2a, E);

    // ---- 5) weighted message aggregation (one wave per edge) ----
    long long tot = (long long)E * 64;
    int ga = (int)((tot + 255) / 256);
    edge_aggr_kernel<<<ga, 256, 0, stream>>>(src_p2p, dst_p2p, es_p2p, ed_p2p, m_p2p, s_p2p, Whp2p, outP, E);
    edge_aggr_kernel<<<ga, 256, 0, stream>>>(src_p2a, dst_p2a, es_p2a, ed_p2a, m_p2a, s_p2a, Whp2a, outA, E);
    edge_aggr_kernel<<<ga, 256, 0, stream>>>(src_a2p, dst_a2p, es_a2p, ed_a2p, m_a2p, s_a2p, Wha2p, outP, E);
    edge_aggr_kernel<<<ga, 256, 0, stream>>>(src_a2a, dst_a2a, es_a2a, ed_a2a, m_a2a, s_a2a, Wha2a, outA, E);

    // ---- 6) final ReLU over both outputs ----
    {
        int n4 = (NP + NA) * 32;   // (NP+NA)*128/4
        relu_kernel<<<(n4 + 255) / 256, 256, 0, stream>>>((float4*)d_out, n4);
    }
}

// Round 2
// 1273.643 us; speedup vs baseline: 2.2988x; 2.2988x over previous
//
#include <hip/hip_runtime.h>
#include <float.h>

#define ALPHA 0.2f
__device__ __forceinline__ float leakyf(float x) { return x > 0.0f ? x : ALPHA * x; }

struct Ptr4i { const int* p0; const int* p1; const int* p2; const int* p3; };

// ---------- dot epilogue: red[r][q] = sum_c acc[r][q]*att[q*32+c] over the 32-lane group ----------
__device__ __forceinline__ void dot_epilogue(const float acc[4][4], const float* __restrict__ att,
                                             float* __restrict__ o, int c, int baserow, int N)
{
    float red[4][4];
    #pragma unroll
    for (int r = 0; r < 4; ++r)
        #pragma unroll
        for (int q = 0; q < 4; ++q) red[r][q] = acc[r][q] * att[q * 32 + c];
    #pragma unroll
    for (int r = 0; r < 4; ++r)
        #pragma unroll
        for (int q = 0; q < 4; ++q)
            #pragma unroll
            for (int off = 1; off < 32; off <<= 1)
                red[r][q] += __shfl_xor(red[r][q], off, 64);
    #pragma unroll
    for (int r = 0; r < 4; ++r) {
        int row = baserow + r;
        if (row < N) {
            #pragma unroll
            for (int q = 0; q < 4; ++q)
                if (c == r * 4 + q) o[(size_t)row * 4 + q] = red[r][q];
        }
    }
}

// ---------- fused 3-matrix linear + attention-dot epilogues ----------
// x: [N,128], W: [128,128] (y = x@W + b), o: [N,128]. 32 rows/block, 256 thr, 4x4 micro-tile.
__global__ __launch_bounds__(256) void lin3_kernel(
    const float* __restrict__ x, int N,
    const float* __restrict__ W0, const float* __restrict__ b0, float* __restrict__ o0,
    const float* __restrict__ attA0, float* __restrict__ dotA0,
    const float* __restrict__ attB0, float* __restrict__ dotB0,
    const float* __restrict__ W1, const float* __restrict__ b1, float* __restrict__ o1,
    const float* __restrict__ attA1, float* __restrict__ dotA1,
    const float* __restrict__ W2, const float* __restrict__ b2, float* __restrict__ o2,
    const float* __restrict__ attA2, float* __restrict__ dotA2)
{
    __shared__ float xs[32 * 128];
    const int row0 = blockIdx.x * 32;
    {
        float4* xl = (float4*)xs;
        #pragma unroll
        for (int ii = 0; ii < 4; ++ii) {
            int i = threadIdx.x + 256 * ii;          // float4 index in [0,1024)
            int r = i >> 5;
            int srcrow = row0 + r;
            if (srcrow >= N) srcrow = N - 1;
            xl[i] = ((const float4*)x)[(size_t)srcrow * 32 + (i & 31)];
        }
    }
    __syncthreads();
    const int c  = threadIdx.x & 31;        // col base (cols c, c+32, c+64, c+96 -> head q, dim c)
    const int r0 = (threadIdx.x >> 5) << 2; // 4 rows per thread

    const float* Wm[3]  = {W0, W1, W2};
    const float* bm[3]  = {b0, b1, b2};
    float*       om[3]  = {o0, o1, o2};
    const float* aAm[3] = {attA0, attA1, attA2};
    float*       dAm[3] = {dotA0, dotA1, dotA2};

    #pragma unroll
    for (int m = 0; m < 3; ++m) {
        const float* __restrict__ W = Wm[m];
        float acc[4][4] = {};
        #pragma unroll 4
        for (int k = 0; k < 128; ++k) {
            float w[4];
            #pragma unroll
            for (int q = 0; q < 4; ++q) w[q] = W[k * 128 + c + 32 * q];
            #pragma unroll
            for (int r = 0; r < 4; ++r) {
                float xv = xs[(r0 + r) * 128 + k];
                #pragma unroll
                for (int q = 0; q < 4; ++q) acc[r][q] += xv * w[q];
            }
        }
        // add bias into acc (dots must include bias)
        #pragma unroll
        for (int q = 0; q < 4; ++q) {
            float bb = bm[m][c + 32 * q];
            #pragma unroll
            for (int r = 0; r < 4; ++r) acc[r][q] += bb;
        }
        // store
        #pragma unroll
        for (int r = 0; r < 4; ++r) {
            int row = row0 + r0 + r;
            if (row < N) {
                float* orow = om[m] + (size_t)row * 128;
                #pragma unroll
                for (int q = 0; q < 4; ++q) orow[c + 32 * q] = acc[r][q];
            }
        }
        // attention dots
        if (aAm[m]) dot_epilogue(acc, aAm[m], dAm[m], c, row0 + r0, N);
        if (m == 0 && attB0) dot_epilogue(acc, attB0, dotB0, c, row0 + r0, N);
    }
}

// ---------- zero fill ----------
__global__ __launch_bounds__(256) void zero_kernel(int* __restrict__ p, int n) {
    int i = blockIdx.x * 256 + threadIdx.x;
    if (i < n) p[i] = 0;
}

// ---------- CSR build: degree count ----------
__global__ __launch_bounds__(256) void count_kernel(Ptr4i dsts, int* __restrict__ deg, int stride, int E) {
    int i = blockIdx.x * 256 + threadIdx.x;
    if (i >= E) return;
    int r = blockIdx.y;
    const int* dst = (r == 0) ? dsts.p0 : (r == 1) ? dsts.p1 : (r == 2) ? dsts.p2 : dsts.p3;
    atomicAdd(deg + (size_t)r * stride + dst[i], 1);
}

// ---------- CSR build: exclusive scan (one block per relation) ----------
__global__ __launch_bounds__(256) void scan_kernel(const int* __restrict__ deg, int* __restrict__ start,
                                                   int* __restrict__ pos, int stride, int4 Ns)
{
    int r = blockIdx.x;
    int N = (r == 0) ? Ns.x : (r == 1) ? Ns.y : (r == 2) ? Ns.z : Ns.w;
    const int* dg = deg + (size_t)r * stride;
    int* st = start + (size_t)r * stride;
    int* ps = pos + (size_t)r * stride;
    int t = threadIdx.x;
    int chunk = (N + 255) >> 8;
    int lo = t * chunk;
    int hi = min(lo + chunk, N);
    int s = 0;
    for (int i = lo; i < hi; ++i) s += dg[i];
    __shared__ int sums[256];
    sums[t] = s;
    __syncthreads();
    for (int off = 1; off < 256; off <<= 1) {
        int y = (t >= off) ? sums[t - off] : 0;
        __syncthreads();
        sums[t] += y;
        __syncthreads();
    }
    int run = sums[t] - s;   // exclusive prefix of this thread's chunk
    for (int i = lo; i < hi; ++i) { st[i] = run; ps[i] = run; run += dg[i]; }
}

// ---------- CSR build: scatter edge ids ----------
__global__ __launch_bounds__(256) void scatter_kernel(Ptr4i dsts, int* __restrict__ pos, int stride,
                                                      int* __restrict__ eidx, int E) {
    int i = blockIdx.x * 256 + threadIdx.x;
    if (i >= E) return;
    int r = blockIdx.y;
    const int* dst = (r == 0) ? dsts.p0 : (r == 1) ? dsts.p1 : (r == 2) ? dsts.p2 : dsts.p3;
    int p = atomicAdd(pos + (size_t)r * stride + dst[i], 1);
    eidx[(size_t)r * E + p] = i;
}

// ---------- per-dst fused GAT: online softmax + gather + self + relu, one wave per node ----------
__global__ __launch_bounds__(256) void gat_node_kernel(
    float* __restrict__ out, int Nd,
    const int* __restrict__ start0, const int* __restrict__ deg0, const int* __restrict__ eidx0,
    const int* __restrict__ src0, const float* __restrict__ Wh0,
    const float* __restrict__ es0, const float* __restrict__ ed0,
    const int* __restrict__ start1, const int* __restrict__ deg1, const int* __restrict__ eidx1,
    const int* __restrict__ src1, const float* __restrict__ Wh1,
    const float* __restrict__ es1, const float* __restrict__ ed1)
{
    int gid = blockIdx.x * 256 + threadIdx.x;
    int d = gid >> 6;
    if (d >= Nd) return;
    int lane = threadIdx.x & 63;
    int h2 = lane >> 4;                      // head of output dims (lane*2, lane*2+1)
    float2 acc = *(const float2*)(out + (size_t)d * 128 + lane * 2);   // self term from lin3

    #pragma unroll
    for (int rel = 0; rel < 2; ++rel) {
        const int*   start = rel ? start1 : start0;
        const int*   deg   = rel ? deg1   : deg0;
        const int*   eidx  = rel ? eidx1  : eidx0;
        const int*   src   = rel ? src1   : src0;
        const float* Wh    = rel ? Wh1    : Wh0;
        const float* es    = rel ? es1    : es0;
        const float* ed    = rel ? ed1    : ed0;

        int st = start[d];
        int n  = deg[d];
        if (n > 0) {
            float edv = ed[(size_t)d * 4 + h2];
            float mx = -FLT_MAX, sum = 0.f;
            float2 am = {0.f, 0.f};
            for (int j = 0; j < n; ++j) {
                int e = eidx[st + j];
                int s = src[e];
                float ev = leakyf(es[(size_t)s * 4 + h2] + edv);
                float nm = fmaxf(mx, ev);
                float sc = __expf(mx - nm);
                float p  = __expf(ev - nm);
                sum = sum * sc + p;
                float2 w = *(const float2*)(Wh + (size_t)s * 128 + lane * 2);
                am.x = am.x * sc + w.x * p;
                am.y = am.y * sc + w.y * p;
                mx = nm;
            }
            float inv = 1.0f / sum;
            acc.x += am.x * inv;
            acc.y += am.y * inv;
        }
    }
    acc.x = fmaxf(acc.x, 0.f);
    acc.y = fmaxf(acc.y, 0.f);
    *(float2*)(out + (size_t)d * 128 + lane * 2) = acc;
}

extern "C" void kernel_launch(void* const* d_in, const int* in_sizes, int n_in,
                              void* d_out, int out_size, void* d_ws, size_t ws_size,
                              hipStream_t stream)
{
    const float* feat_P = (const float*)d_in[0];
    const float* feat_A = (const float*)d_in[1];
    const int* src_p2p = (const int*)d_in[2];
    const int* dst_p2p = (const int*)d_in[3];
    const int* src_p2a = (const int*)d_in[4];
    const int* dst_p2a = (const int*)d_in[5];
    const int* src_a2p = (const int*)d_in[6];
    const int* dst_a2p = (const int*)d_in[7];
    const int* src_a2a = (const int*)d_in[8];
    const int* dst_a2a = (const int*)d_in[9];
    const float* W_P   = (const float*)d_in[10]; const float* b_P   = (const float*)d_in[11];
    const float* W_A   = (const float*)d_in[12]; const float* b_A   = (const float*)d_in[13];
    const float* W_p2p = (const float*)d_in[14]; const float* b_p2p = (const float*)d_in[15];
    const float* W_p2a = (const float*)d_in[16]; const float* b_p2a = (const float*)d_in[17];
    const float* W_a2p = (const float*)d_in[18]; const float* b_a2p = (const float*)d_in[19];
    const float* W_a2a = (const float*)d_in[20]; const float* b_a2a = (const float*)d_in[21];
    const float* att_p2p_src = (const float*)d_in[22];
    const float* att_p2p_dst = (const float*)d_in[23];
    const float* att_p2a_src = (const float*)d_in[24];
    const float* att_p2a_dst = (const float*)d_in[25];
    const float* att_a2p_src = (const float*)d_in[26];
    const float* att_a2p_dst = (const float*)d_in[27];
    const float* att_a2a_src = (const float*)d_in[28];
    const float* att_a2a_dst = (const float*)d_in[29];

    const int NP = in_sizes[0] / 128;
    const int NA = in_sizes[1] / 128;
    const int E  = in_sizes[2];
    const int stride = (NP > NA) ? NP : NA;

    float* outP = (float*)d_out;
    float* outA = (float*)d_out + (size_t)NP * 128;

    // ---- workspace layout ----
    char* ws = (char*)d_ws;
    size_t off = 0;
    auto alloc = [&](size_t bytes) -> void* {
        void* p = ws + off;
        off += (bytes + 255) & ~(size_t)255;
        return p;
    };
    float* Whp2p = (float*)alloc((size_t)NP * 128 * 4);
    float* Whp2a = (float*)alloc((size_t)NP * 128 * 4);
    float* Wha2p = (float*)alloc((size_t)NA * 128 * 4);
    float* Wha2a = (float*)alloc((size_t)NA * 128 * 4);
    float* es_p2p = (float*)alloc((size_t)NP * 16);
    float* es_p2a = (float*)alloc((size_t)NP * 16);
    float* es_a2p = (float*)alloc((size_t)NA * 16);
    float* es_a2a = (float*)alloc((size_t)NA * 16);
    float* ed_p2p = (float*)alloc((size_t)NP * 16);
    float* ed_a2p = (float*)alloc((size_t)NP * 16);
    float* ed_p2a = (float*)alloc((size_t)NA * 16);
    float* ed_a2a = (float*)alloc((size_t)NA * 16);
    int* deg   = (int*)alloc((size_t)4 * stride * 4);
    int* start = (int*)alloc((size_t)4 * stride * 4);
    int* pos   = (int*)alloc((size_t)4 * stride * 4);
    int* eidx  = (int*)alloc((size_t)4 * E * 4);

    // relation order for CSR: 0=p2p(dst P), 1=a2p(dst P), 2=p2a(dst A), 3=a2a(dst A)
    Ptr4i dsts = {dst_p2p, dst_a2p, dst_p2a, dst_a2a};

    // ---- 1) fused linears + dot epilogues (self terms straight into d_out) ----
    lin3_kernel<<<(NP + 31) / 32, 256, 0, stream>>>(feat_P, NP,
        W_P,   b_P,   outP,  att_p2p_dst, ed_p2p, att_a2p_dst, ed_a2p,
        W_p2p, b_p2p, Whp2p, att_p2p_src, es_p2p,
        W_p2a, b_p2a, Whp2a, att_p2a_src, es_p2a);
    lin3_kernel<<<(NA + 31) / 32, 256, 0, stream>>>(feat_A, NA,
        W_A,   b_A,   outA,  att_p2a_dst, ed_p2a, att_a2a_dst, ed_a2a,
        W_a2p, b_a2p, Wha2p, att_a2p_src, es_a2p,
        W_a2a, b_a2a, Wha2a, att_a2a_src, es_a2a);

    // ---- 2) CSR build ----
    zero_kernel<<<(4 * stride + 255) / 256, 256, 0, stream>>>(deg, 4 * stride);
    {
        dim3 g((E + 255) / 256, 4);
        count_kernel<<<g, 256, 0, stream>>>(dsts, deg, stride, E);
        scan_kernel<<<4, 256, 0, stream>>>(deg, start, pos, stride,
                                           make_int4(NP, NP, NA, NA));
        scatter_kernel<<<g, 256, 0, stream>>>(dsts, pos, stride, eidx, E);
    }

    // ---- 3) fused per-dst aggregation (+self +relu), one wave per node ----
    gat_node_kernel<<<(NP * 64 + 255) / 256, 256, 0, stream>>>(outP, NP,
        start + 0 * (size_t)stride, deg + 0 * (size_t)stride, eidx + 0 * (size_t)E, src_p2p, Whp2p, es_p2p, ed_p2p,
        start + 1 * (size_t)stride, deg + 1 * (size_t)stride, eidx + 1 * (size_t)E, src_a2p, Wha2p, es_a2p, ed_a2p);
    gat_node_kernel<<<(NA * 64 + 255) / 256, 256, 0, stream>>>(outA, NA,
        start + 2 * (size_t)stride, deg + 2 * (size_t)stride, eidx + 2 * (size_t)E, src_p2a, Whp2a, es_p2a, ed_p2a,
        start + 3 * (size_t)stride, deg + 3 * (size_t)stride, eidx + 3 * (size_t)E, src_a2a, Wha2a, es_a2a, ed_a2a);
}

// Round 3
// 1068.667 us; speedup vs baseline: 2.7397x; 1.1918x over previous
//
#include <hip/hip_runtime.h>
#include <float.h>

#define ALPHA 0.2f
__device__ __forceinline__ float leakyf(float x) { return x > 0.0f ? x : ALPHA * x; }

struct Ptr4i { const int* p0; const int* p1; const int* p2; const int* p3; };

// ---------- dot epilogue: per (row r, head q): dot(acc_row_head, att_head) across 32-lane group ----------
__device__ __forceinline__ void dot_epilogue(const float acc[4][4], const float* __restrict__ att,
                                             float* __restrict__ o, int c, int baserow, int N)
{
    float red[4][4];
    #pragma unroll
    for (int r = 0; r < 4; ++r)
        #pragma unroll
        for (int q = 0; q < 4; ++q) red[r][q] = acc[r][q] * att[q * 32 + c];
    #pragma unroll
    for (int r = 0; r < 4; ++r)
        #pragma unroll
        for (int q = 0; q < 4; ++q)
            #pragma unroll
            for (int off = 1; off < 32; off <<= 1)
                red[r][q] += __shfl_xor(red[r][q], off, 64);
    #pragma unroll
    for (int r = 0; r < 4; ++r) {
        int row = baserow + r;
        if (row < N) {
            #pragma unroll
            for (int q = 0; q < 4; ++q)
                if (c == r * 4 + q) o[(size_t)row * 4 + q] = red[r][q];
        }
    }
}

// ---------- fused 3-matrix linear + attention-dot epilogues ----------
__global__ __launch_bounds__(256) void lin3_kernel(
    const float* __restrict__ x, int N,
    const float* __restrict__ W0, const float* __restrict__ b0, float* __restrict__ o0,
    const float* __restrict__ attA0, float* __restrict__ dotA0,
    const float* __restrict__ attB0, float* __restrict__ dotB0,
    const float* __restrict__ W1, const float* __restrict__ b1, float* __restrict__ o1,
    const float* __restrict__ attA1, float* __restrict__ dotA1,
    const float* __restrict__ W2, const float* __restrict__ b2, float* __restrict__ o2,
    const float* __restrict__ attA2, float* __restrict__ dotA2)
{
    __shared__ float xs[32 * 128];
    const int row0 = blockIdx.x * 32;
    {
        float4* xl = (float4*)xs;
        #pragma unroll
        for (int ii = 0; ii < 4; ++ii) {
            int i = threadIdx.x + 256 * ii;
            int r = i >> 5;
            int srcrow = row0 + r;
            if (srcrow >= N) srcrow = N - 1;
            xl[i] = ((const float4*)x)[(size_t)srcrow * 32 + (i & 31)];
        }
    }
    __syncthreads();
    const int c  = threadIdx.x & 31;
    const int r0 = (threadIdx.x >> 5) << 2;

    const float* Wm[3]  = {W0, W1, W2};
    const float* bm[3]  = {b0, b1, b2};
    float*       om[3]  = {o0, o1, o2};
    const float* aAm[3] = {attA0, attA1, attA2};
    float*       dAm[3] = {dotA0, dotA1, dotA2};

    #pragma unroll
    for (int m = 0; m < 3; ++m) {
        const float* __restrict__ W = Wm[m];
        float acc[4][4] = {};
        #pragma unroll 4
        for (int k = 0; k < 128; ++k) {
            float w[4];
            #pragma unroll
            for (int q = 0; q < 4; ++q) w[q] = W[k * 128 + c + 32 * q];
            #pragma unroll
            for (int r = 0; r < 4; ++r) {
                float xv = xs[(r0 + r) * 128 + k];
                #pragma unroll
                for (int q = 0; q < 4; ++q) acc[r][q] += xv * w[q];
            }
        }
        #pragma unroll
        for (int q = 0; q < 4; ++q) {
            float bb = bm[m][c + 32 * q];
            #pragma unroll
            for (int r = 0; r < 4; ++r) acc[r][q] += bb;
        }
        #pragma unroll
        for (int r = 0; r < 4; ++r) {
            int row = row0 + r0 + r;
            if (row < N) {
                float* orow = om[m] + (size_t)row * 128;
                #pragma unroll
                for (int q = 0; q < 4; ++q) orow[c + 32 * q] = acc[r][q];
            }
        }
        if (aAm[m]) dot_epilogue(acc, aAm[m], dAm[m], c, row0 + r0, N);
        if (m == 0 && attB0) dot_epilogue(acc, attB0, dotB0, c, row0 + r0, N);
    }
}

// ---------- zero fill ----------
__global__ __launch_bounds__(256) void zero_kernel(int* __restrict__ p, int n) {
    int i = blockIdx.x * 256 + threadIdx.x;
    if (i < n) p[i] = 0;
}

// ---------- CSR build: degree count ----------
__global__ __launch_bounds__(256) void count_kernel(Ptr4i dsts, int* __restrict__ deg, int stride, int E) {
    int i = blockIdx.x * 256 + threadIdx.x;
    if (i >= E) return;
    int r = blockIdx.y;
    const int* dst = (r == 0) ? dsts.p0 : (r == 1) ? dsts.p1 : (r == 2) ? dsts.p2 : dsts.p3;
    atomicAdd(deg + (size_t)r * stride + dst[i], 1);
}

// ---------- parallel scan stage 1: per-block partial sums (4096 items/block) ----------
__global__ __launch_bounds__(256) void scan_partial_kernel(
    const int* __restrict__ deg, int stride, int4 Ns, int* __restrict__ blksum, int nblk)
{
    int r = blockIdx.y;
    int N = (r == 0) ? Ns.x : (r == 1) ? Ns.y : (r == 2) ? Ns.z : Ns.w;
    const int* dg = deg + (size_t)r * stride;
    int base = blockIdx.x * 4096 + threadIdx.x * 16;
    int s = 0;
    #pragma unroll 4
    for (int i = 0; i < 16; ++i) {
        int idx = base + i;
        if (idx < N) s += dg[idx];
    }
    #pragma unroll
    for (int off = 1; off < 64; off <<= 1) s += __shfl_xor(s, off, 64);
    __shared__ int wsum[4];
    if ((threadIdx.x & 63) == 0) wsum[threadIdx.x >> 6] = s;
    __syncthreads();
    if (threadIdx.x == 0)
        blksum[(size_t)r * nblk + blockIdx.x] = wsum[0] + wsum[1] + wsum[2] + wsum[3];
}

// ---------- parallel scan stage 2: exclusive scan of block sums (tiny) ----------
__global__ __launch_bounds__(64) void scan_blksum_kernel(int* __restrict__ blksum, int nblk) {
    int r = threadIdx.x;
    if (r >= 4) return;
    int* bs = blksum + (size_t)r * nblk;
    int run = 0;
    for (int i = 0; i < nblk; ++i) { int v = bs[i]; bs[i] = run; run += v; }
}

// ---------- parallel scan stage 3: per-block exclusive write-out ----------
__global__ __launch_bounds__(256) void scan_write_kernel(
    const int* __restrict__ deg, const int* __restrict__ blksum, int stride, int4 Ns, int nblk,
    int* __restrict__ start, int* __restrict__ pos)
{
    int r = blockIdx.y;
    int N = (r == 0) ? Ns.x : (r == 1) ? Ns.y : (r == 2) ? Ns.z : Ns.w;
    const int* dg = deg + (size_t)r * stride;
    int base = blockIdx.x * 4096 + threadIdx.x * 16;
    int vals[16];
    int s = 0;
    #pragma unroll 4
    for (int i = 0; i < 16; ++i) {
        int idx = base + i;
        vals[i] = (idx < N) ? dg[idx] : 0;
        s += vals[i];
    }
    __shared__ int sums[256];
    sums[threadIdx.x] = s;
    __syncthreads();
    #pragma unroll
    for (int off = 1; off < 256; off <<= 1) {
        int y = (threadIdx.x >= off) ? sums[threadIdx.x - off] : 0;
        __syncthreads();
        sums[threadIdx.x] += y;
        __syncthreads();
    }
    int run = sums[threadIdx.x] - s + blksum[(size_t)r * nblk + blockIdx.x];
    int* st = start + (size_t)r * stride;
    int* ps = pos + (size_t)r * stride;
    #pragma unroll 4
    for (int i = 0; i < 16; ++i) {
        int idx = base + i;
        if (idx < N) { st[idx] = run; ps[idx] = run; run += vals[i]; }
    }
}

// ---------- CSR build: scatter SRC node ids (not edge ids) ----------
__global__ __launch_bounds__(256) void scatter_kernel(Ptr4i dsts, Ptr4i srcs, int* __restrict__ pos,
                                                      int stride, int* __restrict__ csrc, int E) {
    int i = blockIdx.x * 256 + threadIdx.x;
    if (i >= E) return;
    int r = blockIdx.y;
    const int* dst = (r == 0) ? dsts.p0 : (r == 1) ? dsts.p1 : (r == 2) ? dsts.p2 : dsts.p3;
    const int* src = (r == 0) ? srcs.p0 : (r == 1) ? srcs.p1 : (r == 2) ? srcs.p2 : srcs.p3;
    int p = atomicAdd(pos + (size_t)r * stride + dst[i], 1);
    csrc[(size_t)r * E + p] = src[i];
}

// ---------- per-dst fused GAT: 2-pass softmax + gather + self + relu, one wave per node ----------
__global__ __launch_bounds__(256) void gat_node_kernel(
    float* __restrict__ out, int Nd,
    const int* __restrict__ start0, const int* __restrict__ deg0, const int* __restrict__ csrc0,
    const float* __restrict__ Wh0, const float* __restrict__ es0, const float* __restrict__ ed0,
    const int* __restrict__ start1, const int* __restrict__ deg1, const int* __restrict__ csrc1,
    const float* __restrict__ Wh1, const float* __restrict__ es1, const float* __restrict__ ed1)
{
    int gid = blockIdx.x * 256 + threadIdx.x;
    int d = gid >> 6;
    if (d >= Nd) return;
    int lane = threadIdx.x & 63;
    int h2 = lane >> 4;
    float2 acc = *(const float2*)(out + (size_t)d * 128 + lane * 2);

    #pragma unroll
    for (int rel = 0; rel < 2; ++rel) {
        const int*   start = rel ? start1 : start0;
        const int*   deg   = rel ? deg1   : deg0;
        const int*   csrc  = rel ? csrc1  : csrc0;
        const float* Wh    = rel ? Wh1    : Wh0;
        const float* es    = rel ? es1    : es0;
        const float* ed    = rel ? ed1    : ed0;

        int st = start[d];
        int n  = deg[d];
        if (n > 0) {
            float edv = ed[(size_t)d * 4 + h2];
            // pass 1: max
            float mx = -FLT_MAX;
            for (int j = 0; j < n; ++j) {
                int s = csrc[st + j];
                mx = fmaxf(mx, leakyf(es[(size_t)s * 4 + h2] + edv));
            }
            // pass 2: sum + weighted accumulate
            float sum = 0.f;
            float2 am = {0.f, 0.f};
            for (int j = 0; j < n; ++j) {
                int s = csrc[st + j];
                float p = __expf(leakyf(es[(size_t)s * 4 + h2] + edv) - mx);
                float2 w = *(const float2*)(Wh + (size_t)s * 128 + lane * 2);
                sum += p;
                am.x += w.x * p;
                am.y += w.y * p;
            }
            float inv = 1.0f / sum;
            acc.x += am.x * inv;
            acc.y += am.y * inv;
        }
    }
    acc.x = fmaxf(acc.x, 0.f);
    acc.y = fmaxf(acc.y, 0.f);
    *(float2*)(out + (size_t)d * 128 + lane * 2) = acc;
}

extern "C" void kernel_launch(void* const* d_in, const int* in_sizes, int n_in,
                              void* d_out, int out_size, void* d_ws, size_t ws_size,
                              hipStream_t stream)
{
    const float* feat_P = (const float*)d_in[0];
    const float* feat_A = (const float*)d_in[1];
    const int* src_p2p = (const int*)d_in[2];
    const int* dst_p2p = (const int*)d_in[3];
    const int* src_p2a = (const int*)d_in[4];
    const int* dst_p2a = (const int*)d_in[5];
    const int* src_a2p = (const int*)d_in[6];
    const int* dst_a2p = (const int*)d_in[7];
    const int* src_a2a = (const int*)d_in[8];
    const int* dst_a2a = (const int*)d_in[9];
    const float* W_P   = (const float*)d_in[10]; const float* b_P   = (const float*)d_in[11];
    const float* W_A   = (const float*)d_in[12]; const float* b_A   = (const float*)d_in[13];
    const float* W_p2p = (const float*)d_in[14]; const float* b_p2p = (const float*)d_in[15];
    const float* W_p2a = (const float*)d_in[16]; const float* b_p2a = (const float*)d_in[17];
    const float* W_a2p = (const float*)d_in[18]; const float* b_a2p = (const float*)d_in[19];
    const float* W_a2a = (const float*)d_in[20]; const float* b_a2a = (const float*)d_in[21];
    const float* att_p2p_src = (const float*)d_in[22];
    const float* att_p2p_dst = (const float*)d_in[23];
    const float* att_p2a_src = (const float*)d_in[24];
    const float* att_p2a_dst = (const float*)d_in[25];
    const float* att_a2p_src = (const float*)d_in[26];
    const float* att_a2p_dst = (const float*)d_in[27];
    const float* att_a2a_src = (const float*)d_in[28];
    const float* att_a2a_dst = (const float*)d_in[29];

    const int NP = in_sizes[0] / 128;
    const int NA = in_sizes[1] / 128;
    const int E  = in_sizes[2];
    const int stride = (NP > NA) ? NP : NA;
    const int nblk = (stride + 4095) / 4096;

    float* outP = (float*)d_out;
    float* outA = (float*)d_out + (size_t)NP * 128;

    char* ws = (char*)d_ws;
    size_t off = 0;
    auto alloc = [&](size_t bytes) -> void* {
        void* p = ws + off;
        off += (bytes + 255) & ~(size_t)255;
        return p;
    };
    float* Whp2p = (float*)alloc((size_t)NP * 128 * 4);
    float* Whp2a = (float*)alloc((size_t)NP * 128 * 4);
    float* Wha2p = (float*)alloc((size_t)NA * 128 * 4);
    float* Wha2a = (float*)alloc((size_t)NA * 128 * 4);
    float* es_p2p = (float*)alloc((size_t)NP * 16);
    float* es_p2a = (float*)alloc((size_t)NP * 16);
    float* es_a2p = (float*)alloc((size_t)NA * 16);
    float* es_a2a = (float*)alloc((size_t)NA * 16);
    float* ed_p2p = (float*)alloc((size_t)NP * 16);
    float* ed_a2p = (float*)alloc((size_t)NP * 16);
    float* ed_p2a = (float*)alloc((size_t)NA * 16);
    float* ed_a2a = (float*)alloc((size_t)NA * 16);
    int* deg    = (int*)alloc((size_t)4 * stride * 4);
    int* start  = (int*)alloc((size_t)4 * stride * 4);
    int* pos    = (int*)alloc((size_t)4 * stride * 4);
    int* csrc   = (int*)alloc((size_t)4 * E * 4);
    int* blksum = (int*)alloc((size_t)4 * nblk * 4);

    // relation order: 0=p2p(dst P), 1=a2p(dst P), 2=p2a(dst A), 3=a2a(dst A)
    Ptr4i dsts = {dst_p2p, dst_a2p, dst_p2a, dst_a2a};
    Ptr4i srcs = {src_p2p, src_a2p, src_p2a, src_a2a};
    int4 Ns = make_int4(NP, NP, NA, NA);

    // ---- 1) fused linears + dot epilogues ----
    lin3_kernel<<<(NP + 31) / 32, 256, 0, stream>>>(feat_P, NP,
        W_P,   b_P,   outP,  att_p2p_dst, ed_p2p, att_a2p_dst, ed_a2p,
        W_p2p, b_p2p, Whp2p, att_p2p_src, es_p2p,
        W_p2a, b_p2a, Whp2a, att_p2a_src, es_p2a);
    lin3_kernel<<<(NA + 31) / 32, 256, 0, stream>>>(feat_A, NA,
        W_A,   b_A,   outA,  att_p2a_dst, ed_p2a, att_a2a_dst, ed_a2a,
        W_a2p, b_a2p, Wha2p, att_a2p_src, es_a2p,
        W_a2a, b_a2a, Wha2a, att_a2a_src, es_a2a);

    // ---- 2) CSR build (parallel scan) ----
    zero_kernel<<<(4 * stride + 255) / 256, 256, 0, stream>>>(deg, 4 * stride);
    {
        dim3 ge((E + 255) / 256, 4);
        dim3 gs(nblk, 4);
        count_kernel<<<ge, 256, 0, stream>>>(dsts, deg, stride, E);
        scan_partial_kernel<<<gs, 256, 0, stream>>>(deg, stride, Ns, blksum, nblk);
        scan_blksum_kernel<<<1, 64, 0, stream>>>(blksum, nblk);
        scan_write_kernel<<<gs, 256, 0, stream>>>(deg, blksum, stride, Ns, nblk, start, pos);
        scatter_kernel<<<ge, 256, 0, stream>>>(dsts, srcs, pos, stride, csrc, E);
    }

    // ---- 3) fused per-dst aggregation (+self +relu), one wave per node ----
    gat_node_kernel<<<(NP * 64 + 255) / 256, 256, 0, stream>>>(outP, NP,
        start + 0 * (size_t)stride, deg + 0 * (size_t)stride, csrc + 0 * (size_t)E, Whp2p, es_p2p, ed_p2p,
        start + 1 * (size_t)stride, deg + 1 * (size_t)stride, csrc + 1 * (size_t)E, Wha2p, es_a2p, ed_a2p);
    gat_node_kernel<<<(NA * 64 + 255) / 256, 256, 0, stream>>>(outA, NA,
        start + 2 * (size_t)stride, deg + 2 * (size_t)stride, csrc + 2 * (size_t)E, Whp2a, es_p2a, ed_p2a,
        start + 3 * (size_t)stride, deg + 3 * (size_t)stride, csrc + 3 * (size_t)E, Wha2a, es_a2a, ed_a2a);
}

// Round 4
// 788.167 us; speedup vs baseline: 3.7147x; 1.3559x over previous
//
#include <hip/hip_runtime.h>
#include <float.h>

#define ALPHA 0.2f
__device__ __forceinline__ float leakyf(float x) { return x > 0.0f ? x : ALPHA * x; }

__device__ __forceinline__ float bf2f(unsigned short u) {
    return __uint_as_float((unsigned)u << 16);
}
__device__ __forceinline__ unsigned short f2bf(float f) {
    unsigned u = __float_as_uint(f);
    return (unsigned short)((u + 0x7FFFu + ((u >> 16) & 1u)) >> 16);
}

struct Ptr4i { const int* p0; const int* p1; const int* p2; const int* p3; };

// ---------- 32-row x 128-col tile GEMM: acc[4][4] = x_tile @ W + b (thread: 4 rows, 4 contiguous cols) ----------
__device__ __forceinline__ void gemm_tile(const float* __restrict__ xs, const float* __restrict__ W,
                                          const float* __restrict__ b, int c, int r0, float acc[4][4])
{
    #pragma unroll
    for (int r = 0; r < 4; ++r)
        #pragma unroll
        for (int i = 0; i < 4; ++i) acc[r][i] = 0.f;
    #pragma unroll 4
    for (int k = 0; k < 128; ++k) {
        float4 w4 = ((const float4*)(W + (size_t)k * 128))[c];
        #pragma unroll
        for (int r = 0; r < 4; ++r) {
            float xv = xs[(r0 + r) * 128 + k];
            acc[r][0] += xv * w4.x; acc[r][1] += xv * w4.y;
            acc[r][2] += xv * w4.z; acc[r][3] += xv * w4.w;
        }
    }
    float4 b4 = ((const float4*)b)[c];
    #pragma unroll
    for (int r = 0; r < 4; ++r) {
        acc[r][0] += b4.x; acc[r][1] += b4.y; acc[r][2] += b4.z; acc[r][3] += b4.w;
    }
}

// ---------- attention-dot epilogue: o[row,h] = dot(acc_row_head_h, att[h,:]) ----------
// thread c owns head h=c>>3, in-head cols (c&7)*4 .. +3; reduce across the 8 lanes of each head group.
__device__ __forceinline__ void dot_epilogue4(const float acc[4][4], const float* __restrict__ att,
                                              float* __restrict__ o, int c, int baserow, int N)
{
    int h  = c >> 3;
    int cb = (c & 7) * 4;
    float red[4];
    #pragma unroll
    for (int r = 0; r < 4; ++r) {
        float s = 0.f;
        #pragma unroll
        for (int i = 0; i < 4; ++i) s += acc[r][i] * att[h * 32 + cb + i];
        red[r] = s;
    }
    #pragma unroll
    for (int r = 0; r < 4; ++r)
        #pragma unroll
        for (int off = 1; off < 8; off <<= 1)
            red[r] += __shfl_xor(red[r], off, 64);
    if ((c & 7) == 0) {
        #pragma unroll
        for (int r = 0; r < 4; ++r) {
            int row = baserow + r;
            if (row < N) o[(size_t)row * 4 + h] = red[r];
        }
    }
}

// ---------- fused 3-matrix linear + dot epilogues; o0 fp32 (self), o1/o2 bf16 (relation) ----------
__global__ __launch_bounds__(256) void lin3_kernel(
    const float* __restrict__ x, int N,
    const float* __restrict__ W0, const float* __restrict__ b0, float* __restrict__ o0,
    const float* __restrict__ attA0, float* __restrict__ dotA0,
    const float* __restrict__ attB0, float* __restrict__ dotB0,
    const float* __restrict__ W1, const float* __restrict__ b1, unsigned short* __restrict__ o1,
    const float* __restrict__ attA1, float* __restrict__ dotA1,
    const float* __restrict__ W2, const float* __restrict__ b2, unsigned short* __restrict__ o2,
    const float* __restrict__ attA2, float* __restrict__ dotA2)
{
    __shared__ float xs[32 * 128];
    const int row0 = blockIdx.x * 32;
    {
        float4* xl = (float4*)xs;
        #pragma unroll
        for (int ii = 0; ii < 4; ++ii) {
            int i = threadIdx.x + 256 * ii;
            int r = i >> 5;
            int srcrow = row0 + r;
            if (srcrow >= N) srcrow = N - 1;
            xl[i] = ((const float4*)x)[(size_t)srcrow * 32 + (i & 31)];
        }
    }
    __syncthreads();
    const int c  = threadIdx.x & 31;
    const int r0 = (threadIdx.x >> 5) << 2;
    const int baserow = row0 + r0;
    float acc[4][4];

    // matrix 0: self transform (fp32 out) + two dst-side dots
    gemm_tile(xs, W0, b0, c, r0, acc);
    #pragma unroll
    for (int r = 0; r < 4; ++r) {
        int row = baserow + r;
        if (row < N)
            ((float4*)(o0 + (size_t)row * 128))[c] =
                make_float4(acc[r][0], acc[r][1], acc[r][2], acc[r][3]);
    }
    dot_epilogue4(acc, attA0, dotA0, c, baserow, N);
    dot_epilogue4(acc, attB0, dotB0, c, baserow, N);

    // matrix 1: relation transform (bf16 out) + src-side dot
    gemm_tile(xs, W1, b1, c, r0, acc);
    #pragma unroll
    for (int r = 0; r < 4; ++r) {
        int row = baserow + r;
        if (row < N) {
            ushort4 w;
            w.x = f2bf(acc[r][0]); w.y = f2bf(acc[r][1]);
            w.z = f2bf(acc[r][2]); w.w = f2bf(acc[r][3]);
            ((ushort4*)(o1 + (size_t)row * 128))[c] = w;
        }
    }
    dot_epilogue4(acc, attA1, dotA1, c, baserow, N);

    // matrix 2
    gemm_tile(xs, W2, b2, c, r0, acc);
    #pragma unroll
    for (int r = 0; r < 4; ++r) {
        int row = baserow + r;
        if (row < N) {
            ushort4 w;
            w.x = f2bf(acc[r][0]); w.y = f2bf(acc[r][1]);
            w.z = f2bf(acc[r][2]); w.w = f2bf(acc[r][3]);
            ((ushort4*)(o2 + (size_t)row * 128))[c] = w;
        }
    }
    dot_epilogue4(acc, attA2, dotA2, c, baserow, N);
}

// ---------- zero fill ----------
__global__ __launch_bounds__(256) void zero_kernel(int* __restrict__ p, int n) {
    int i = blockIdx.x * 256 + threadIdx.x;
    if (i < n) p[i] = 0;
}

// ---------- CSR build: degree count ----------
__global__ __launch_bounds__(256) void count_kernel(Ptr4i dsts, int* __restrict__ deg, int stride, int E) {
    int i = blockIdx.x * 256 + threadIdx.x;
    if (i >= E) return;
    int r = blockIdx.y;
    const int* dst = (r == 0) ? dsts.p0 : (r == 1) ? dsts.p1 : (r == 2) ? dsts.p2 : dsts.p3;
    atomicAdd(deg + (size_t)r * stride + dst[i], 1);
}

// ---------- parallel scan stage 1 ----------
__global__ __launch_bounds__(256) void scan_partial_kernel(
    const int* __restrict__ deg, int stride, int4 Ns, int* __restrict__ blksum, int nblk)
{
    int r = blockIdx.y;
    int N = (r == 0) ? Ns.x : (r == 1) ? Ns.y : (r == 2) ? Ns.z : Ns.w;
    const int* dg = deg + (size_t)r * stride;
    int base = blockIdx.x * 4096 + threadIdx.x * 16;
    int s = 0;
    #pragma unroll 4
    for (int i = 0; i < 16; ++i) {
        int idx = base + i;
        if (idx < N) s += dg[idx];
    }
    #pragma unroll
    for (int off = 1; off < 64; off <<= 1) s += __shfl_xor(s, off, 64);
    __shared__ int wsum[4];
    if ((threadIdx.x & 63) == 0) wsum[threadIdx.x >> 6] = s;
    __syncthreads();
    if (threadIdx.x == 0)
        blksum[(size_t)r * nblk + blockIdx.x] = wsum[0] + wsum[1] + wsum[2] + wsum[3];
}

// ---------- parallel scan stage 2 ----------
__global__ __launch_bounds__(64) void scan_blksum_kernel(int* __restrict__ blksum, int nblk) {
    int r = threadIdx.x;
    if (r >= 4) return;
    int* bs = blksum + (size_t)r * nblk;
    int run = 0;
    for (int i = 0; i < nblk; ++i) { int v = bs[i]; bs[i] = run; run += v; }
}

// ---------- parallel scan stage 3 ----------
__global__ __launch_bounds__(256) void scan_write_kernel(
    const int* __restrict__ deg, const int* __restrict__ blksum, int stride, int4 Ns, int nblk,
    int* __restrict__ start, int* __restrict__ pos)
{
    int r = blockIdx.y;
    int N = (r == 0) ? Ns.x : (r == 1) ? Ns.y : (r == 2) ? Ns.z : Ns.w;
    const int* dg = deg + (size_t)r * stride;
    int base = blockIdx.x * 4096 + threadIdx.x * 16;
    int vals[16];
    int s = 0;
    #pragma unroll 4
    for (int i = 0; i < 16; ++i) {
        int idx = base + i;
        vals[i] = (idx < N) ? dg[idx] : 0;
        s += vals[i];
    }
    __shared__ int sums[256];
    sums[threadIdx.x] = s;
    __syncthreads();
    #pragma unroll
    for (int off = 1; off < 256; off <<= 1) {
        int y = (threadIdx.x >= off) ? sums[threadIdx.x - off] : 0;
        __syncthreads();
        sums[threadIdx.x] += y;
        __syncthreads();
    }
    int run = sums[threadIdx.x] - s + blksum[(size_t)r * nblk + blockIdx.x];
    int* st = start + (size_t)r * stride;
    int* ps = pos + (size_t)r * stride;
    #pragma unroll 4
    for (int i = 0; i < 16; ++i) {
        int idx = base + i;
        if (idx < N) { st[idx] = run; ps[idx] = run; run += vals[i]; }
    }
}

// ---------- CSR build: scatter SRC node ids ----------
__global__ __launch_bounds__(256) void scatter_kernel(Ptr4i dsts, Ptr4i srcs, int* __restrict__ pos,
                                                      int stride, int* __restrict__ csrc, int E) {
    int i = blockIdx.x * 256 + threadIdx.x;
    if (i >= E) return;
    int r = blockIdx.y;
    const int* dst = (r == 0) ? dsts.p0 : (r == 1) ? dsts.p1 : (r == 2) ? dsts.p2 : dsts.p3;
    const int* src = (r == 0) ? srcs.p0 : (r == 1) ? srcs.p1 : (r == 2) ? srcs.p2 : srcs.p3;
    int p = atomicAdd(pos + (size_t)r * stride + dst[i], 1);
    csrc[(size_t)r * E + p] = src[i];
}

// ---------- per-dst fused GAT: single-pass no-max softmax, bf16 gather, 2 edges/wave-iter ----------
__global__ __launch_bounds__(256) void gat_node_kernel(
    float* __restrict__ out, int Nd,
    const int* __restrict__ start0, const int* __restrict__ deg0, const int* __restrict__ csrc0,
    const unsigned short* __restrict__ Wh0, const float* __restrict__ es0, const float* __restrict__ ed0,
    const int* __restrict__ start1, const int* __restrict__ deg1, const int* __restrict__ csrc1,
    const unsigned short* __restrict__ Wh1, const float* __restrict__ es1, const float* __restrict__ ed1)
{
    int gid = blockIdx.x * 256 + threadIdx.x;
    int d = gid >> 6;
    if (d >= Nd) return;
    int lane = threadIdx.x & 63;
    int half = lane >> 5;     // which edge-slot this half-wave handles
    int l    = lane & 31;     // dim group: dims 4l..4l+3
    int h    = l >> 3;        // head

    float4 acc = ((const float4*)(out + (size_t)d * 128))[l];   // self term

    #pragma unroll
    for (int rel = 0; rel < 2; ++rel) {
        const int* start = rel ? start1 : start0;
        const int* deg   = rel ? deg1   : deg0;
        const int* csrc  = rel ? csrc1  : csrc0;
        const unsigned short* Wh = rel ? Wh1 : Wh0;
        const float* es  = rel ? es1 : es0;
        const float* ed  = rel ? ed1 : ed0;

        int st = start[d];
        int n  = deg[d];
        if (n == 0) continue;                 // wave-uniform
        float edv = ed[(size_t)d * 4 + h];
        float sum = 0.f;
        float am0 = 0.f, am1 = 0.f, am2 = 0.f, am3 = 0.f;
        for (int j = half; j < n; j += 2) {
            int s = csrc[st + j];
            float p = __expf(leakyf(es[(size_t)s * 4 + h] + edv));
            ushort4 w = ((const ushort4*)(Wh + (size_t)s * 128))[l];
            sum += p;
            am0 += p * bf2f(w.x); am1 += p * bf2f(w.y);
            am2 += p * bf2f(w.z); am3 += p * bf2f(w.w);
        }
        sum += __shfl_xor(sum, 32, 64);
        am0 += __shfl_xor(am0, 32, 64);
        am1 += __shfl_xor(am1, 32, 64);
        am2 += __shfl_xor(am2, 32, 64);
        am3 += __shfl_xor(am3, 32, 64);
        float inv = 1.0f / sum;
        acc.x += am0 * inv; acc.y += am1 * inv;
        acc.z += am2 * inv; acc.w += am3 * inv;
    }
    if (lane < 32) {
        acc.x = fmaxf(acc.x, 0.f); acc.y = fmaxf(acc.y, 0.f);
        acc.z = fmaxf(acc.z, 0.f); acc.w = fmaxf(acc.w, 0.f);
        ((float4*)(out + (size_t)d * 128))[l] = acc;
    }
}

extern "C" void kernel_launch(void* const* d_in, const int* in_sizes, int n_in,
                              void* d_out, int out_size, void* d_ws, size_t ws_size,
                              hipStream_t stream)
{
    const float* feat_P = (const float*)d_in[0];
    const float* feat_A = (const float*)d_in[1];
    const int* src_p2p = (const int*)d_in[2];
    const int* dst_p2p = (const int*)d_in[3];
    const int* src_p2a = (const int*)d_in[4];
    const int* dst_p2a = (const int*)d_in[5];
    const int* src_a2p = (const int*)d_in[6];
    const int* dst_a2p = (const int*)d_in[7];
    const int* src_a2a = (const int*)d_in[8];
    const int* dst_a2a = (const int*)d_in[9];
    const float* W_P   = (const float*)d_in[10]; const float* b_P   = (const float*)d_in[11];
    const float* W_A   = (const float*)d_in[12]; const float* b_A   = (const float*)d_in[13];
    const float* W_p2p = (const float*)d_in[14]; const float* b_p2p = (const float*)d_in[15];
    const float* W_p2a = (const float*)d_in[16]; const float* b_p2a = (const float*)d_in[17];
    const float* W_a2p = (const float*)d_in[18]; const float* b_a2p = (const float*)d_in[19];
    const float* W_a2a = (const float*)d_in[20]; const float* b_a2a = (const float*)d_in[21];
    const float* att_p2p_src = (const float*)d_in[22];
    const float* att_p2p_dst = (const float*)d_in[23];
    const float* att_p2a_src = (const float*)d_in[24];
    const float* att_p2a_dst = (const float*)d_in[25];
    const float* att_a2p_src = (const float*)d_in[26];
    const float* att_a2p_dst = (const float*)d_in[27];
    const float* att_a2a_src = (const float*)d_in[28];
    const float* att_a2a_dst = (const float*)d_in[29];

    const int NP = in_sizes[0] / 128;
    const int NA = in_sizes[1] / 128;
    const int E  = in_sizes[2];
    const int stride = (NP > NA) ? NP : NA;
    const int nblk = (stride + 4095) / 4096;

    float* outP = (float*)d_out;
    float* outA = (float*)d_out + (size_t)NP * 128;

    char* ws = (char*)d_ws;
    size_t off = 0;
    auto alloc = [&](size_t bytes) -> void* {
        void* p = ws + off;
        off += (bytes + 255) & ~(size_t)255;
        return p;
    };
    unsigned short* Whp2p = (unsigned short*)alloc((size_t)NP * 128 * 2);
    unsigned short* Whp2a = (unsigned short*)alloc((size_t)NP * 128 * 2);
    unsigned short* Wha2p = (unsigned short*)alloc((size_t)NA * 128 * 2);
    unsigned short* Wha2a = (unsigned short*)alloc((size_t)NA * 128 * 2);
    float* es_p2p = (float*)alloc((size_t)NP * 16);
    float* es_p2a = (float*)alloc((size_t)NP * 16);
    float* es_a2p = (float*)alloc((size_t)NA * 16);
    float* es_a2a = (float*)alloc((size_t)NA * 16);
    float* ed_p2p = (float*)alloc((size_t)NP * 16);
    float* ed_a2p = (float*)alloc((size_t)NP * 16);
    float* ed_p2a = (float*)alloc((size_t)NA * 16);
    float* ed_a2a = (float*)alloc((size_t)NA * 16);
    int* deg    = (int*)alloc((size_t)4 * stride * 4);
    int* start  = (int*)alloc((size_t)4 * stride * 4);
    int* pos    = (int*)alloc((size_t)4 * stride * 4);
    int* csrc   = (int*)alloc((size_t)4 * E * 4);
    int* blksum = (int*)alloc((size_t)4 * nblk * 4);

    // relation order: 0=p2p(dst P), 1=a2p(dst P), 2=p2a(dst A), 3=a2a(dst A)
    Ptr4i dsts = {dst_p2p, dst_a2p, dst_p2a, dst_a2a};
    Ptr4i srcs = {src_p2p, src_a2p, src_p2a, src_a2a};
    int4 Ns = make_int4(NP, NP, NA, NA);

    // ---- 1) fused linears + dot epilogues ----
    lin3_kernel<<<(NP + 31) / 32, 256, 0, stream>>>(feat_P, NP,
        W_P,   b_P,   outP,  att_p2p_dst, ed_p2p, att_a2p_dst, ed_a2p,
        W_p2p, b_p2p, Whp2p, att_p2p_src, es_p2p,
        W_p2a, b_p2a, Whp2a, att_p2a_src, es_p2a);
    lin3_kernel<<<(NA + 31) / 32, 256, 0, stream>>>(feat_A, NA,
        W_A,   b_A,   outA,  att_p2a_dst, ed_p2a, att_a2a_dst, ed_a2a,
        W_a2p, b_a2p, Wha2p, att_a2p_src, es_a2p,
        W_a2a, b_a2a, Wha2a, att_a2a_src, es_a2a);

    // ---- 2) CSR build ----
    zero_kernel<<<(4 * stride + 255) / 256, 256, 0, stream>>>(deg, 4 * stride);
    {
        dim3 ge((E + 255) / 256, 4);
        dim3 gs(nblk, 4);
        count_kernel<<<ge, 256, 0, stream>>>(dsts, deg, stride, E);
        scan_partial_kernel<<<gs, 256, 0, stream>>>(deg, stride, Ns, blksum, nblk);
        scan_blksum_kernel<<<1, 64, 0, stream>>>(blksum, nblk);
        scan_write_kernel<<<gs, 256, 0, stream>>>(deg, blksum, stride, Ns, nblk, start, pos);
        scatter_kernel<<<ge, 256, 0, stream>>>(dsts, srcs, pos, stride, csrc, E);
    }

    // ---- 3) fused per-dst aggregation (+self +relu) ----
    gat_node_kernel<<<(NP * 64 + 255) / 256, 256, 0, stream>>>(outP, NP,
        start + 0 * (size_t)stride, deg + 0 * (size_t)stride, csrc + 0 * (size_t)E, Whp2p, es_p2p, ed_p2p,
        start + 1 * (size_t)stride, deg + 1 * (size_t)stride, csrc + 1 * (size_t)E, Wha2p, es_a2p, ed_a2p);
    gat_node_kernel<<<(NA * 64 + 255) / 256, 256, 0, stream>>>(outA, NA,
        start + 2 * (size_t)stride, deg + 2 * (size_t)stride, csrc + 2 * (size_t)E, Whp2a, es_p2a, ed_p2a,
        start + 3 * (size_t)stride, deg + 3 * (size_t)stride, csrc + 3 * (size_t)E, Wha2a, es_a2a, ed_a2a);
}

// Round 5
// 584.804 us; speedup vs baseline: 5.0065x; 1.3477x over previous
//
#include <hip/hip_runtime.h>
#include <float.h>

#define ALPHA 0.2f
__device__ __forceinline__ float leakyf(float x) { return x > 0.0f ? x : ALPHA * x; }

__device__ __forceinline__ float bf2f(unsigned short u) {
    return __uint_as_float((unsigned)u << 16);
}
__device__ __forceinline__ unsigned short f2bf(float f) {
    unsigned u = __float_as_uint(f);
    return (unsigned short)((u + 0x7FFFu + ((u >> 16) & 1u)) >> 16);
}

typedef short bf16x8 __attribute__((ext_vector_type(8)));
typedef float f32x4 __attribute__((ext_vector_type(4)));

struct Ptr4i { const int* p0; const int* p1; const int* p2; const int* p3; };
struct PrepM { const float* W; const float* b; const float* attA; const float* attB; };

// ---------- prep: build fragment-linear bf16 W (+ folded attention-dot cols) ----------
// wfrag[mi]: 9 tiles x 4 ksteps x 64 lanes x 8 bf16. Tile t<8: B[k][col=16t+(l&15)],
// k = kstep*32+(l>>4)*8+j. Tile 8: V[k][h] dot-fold cols (0-3 attA, 4-7 attB, rest 0).
__global__ __launch_bounds__(256) void prep_kernel(
    PrepM m0, PrepM m1, PrepM m2, PrepM m3, PrepM m4, PrepM m5,
    bf16x8* __restrict__ wfrag, float* __restrict__ cd)
{
    int mi = blockIdx.x;
    PrepM mm = (mi == 0) ? m0 : (mi == 1) ? m1 : (mi == 2) ? m2 :
               (mi == 3) ? m3 : (mi == 4) ? m4 : m5;
    int part = blockIdx.y;                 // 4 parts x 576 chunks
    for (int ii = 0; ii < 3; ++ii) {
        int c = part * 576 + threadIdx.x + 256 * ii;
        if (c >= part * 576 + 576) continue;
        int t = c >> 8;
        int kstep = (c >> 6) & 3;
        int l = c & 63;
        int k0 = kstep * 32 + (l >> 4) * 8;
        bf16x8 out;
        if (t < 8) {
            int col = t * 16 + (l & 15);
            #pragma unroll
            for (int j = 0; j < 8; ++j)
                out[j] = (short)f2bf(mm.W[(size_t)(k0 + j) * 128 + col]);
        } else {
            int cl = l & 15;
            const float* att = nullptr; int h = 0;
            if (cl < 4 && mm.attA) { att = mm.attA; h = cl; }
            else if (cl >= 4 && cl < 8 && mm.attB) { att = mm.attB; h = cl - 4; }
            #pragma unroll
            for (int j = 0; j < 8; ++j) {
                float s = 0.f;
                if (att) {
                    const float* wrow = mm.W + (size_t)(k0 + j) * 128 + h * 32;
                    for (int d = 0; d < 32; ++d) s += wrow[d] * att[h * 32 + d];
                }
                out[j] = (short)f2bf(s);
            }
        }
        wfrag[(size_t)mi * 2304 + c] = out;
    }
    if (part == 0 && threadIdx.x < 8) {
        int cl = threadIdx.x;
        float s = 0.f;
        const float* att = nullptr; int h = 0;
        if (cl < 4 && mm.attA) { att = mm.attA; h = cl; }
        else if (cl >= 4 && mm.attB) { att = mm.attB; h = cl - 4; }
        if (att) for (int d = 0; d < 32; ++d) s += mm.b[h * 32 + d] * att[h * 32 + d];
        cd[mi * 8 + cl] = s;
    }
}

// ---------- MFMA compute + epilogue for one matrix (W already staged in LDS) ----------
__device__ __forceinline__ void mfma_compute_store(
    const short* xs_s, const short* wl_s, int row0, int N,
    const float* __restrict__ b, float* __restrict__ o32, unsigned short* __restrict__ o16,
    float* __restrict__ dotA, float* __restrict__ dotB, const float* __restrict__ cd)
{
    int l = threadIdx.x & 63, w = threadIdx.x >> 6;
    int cl = l & 15, gq = l >> 4;
    f32x4 acc[9];
    #pragma unroll
    for (int t = 0; t < 9; ++t) acc[t] = (f32x4){0.f, 0.f, 0.f, 0.f};
    int arow = w * 16 + cl;
    #pragma unroll
    for (int ks = 0; ks < 4; ++ks) {
        int k8 = ks * 4 + gq;
        bf16x8 a = *(const bf16x8*)((const char*)xs_s + arow * 256 + ((k8 * 16) ^ ((arow & 7) << 4)));
        #pragma unroll
        for (int t = 0; t < 9; ++t) {
            bf16x8 bf = *(const bf16x8*)((const char*)wl_s + ((t * 4 + ks) * 64 + l) * 16);
            acc[t] = __builtin_amdgcn_mfma_f32_16x16x32_bf16(a, bf, acc[t], 0, 0, 0);
        }
    }
    // C/D layout (m89-verified): col = lane&15, row = (lane>>4)*4 + j
    int rbase = row0 + w * 16 + gq * 4;
    #pragma unroll
    for (int t = 0; t < 8; ++t) {
        int col = t * 16 + cl;
        float bias = b[col];
        #pragma unroll
        for (int j = 0; j < 4; ++j) {
            int row = rbase + j;
            if (row < N) {
                float v = acc[t][j] + bias;
                if (o32) o32[(size_t)row * 128 + col] = v;
                else     o16[(size_t)row * 128 + col] = f2bf(v);
            }
        }
    }
    if (cl < 8) {
        float cdv = cd[cl];
        float* dp = (cl < 4) ? dotA : dotB;
        int h = cl & 3;
        if (dp) {
            #pragma unroll
            for (int j = 0; j < 4; ++j) {
                int row = rbase + j;
                if (row < N) dp[(size_t)row * 4 + h] = acc[8][j] + cdv;
            }
        }
    }
}

// ---------- fused 3-matrix MFMA linear; dots folded as GEMM cols ----------
__global__ __launch_bounds__(256) void lin3_mfma_kernel(
    const float* __restrict__ x, int N,
    const bf16x8* __restrict__ wfrag,   // this call's 3 matrices, 2304 chunks each
    const float* __restrict__ cd,       // 3 x 8 bias-dot constants
    const float* __restrict__ b0, float* __restrict__ o0, float* __restrict__ dA0, float* __restrict__ dB0,
    const float* __restrict__ b1, unsigned short* __restrict__ o1, float* __restrict__ dA1,
    const float* __restrict__ b2, unsigned short* __restrict__ o2, float* __restrict__ dA2)
{
    __shared__ short xs_s[64 * 128];     // 16 KB, XOR-swizzled rows
    __shared__ short wl_s[2304 * 8];     // 36 KB, fragment-linear
    const int row0 = blockIdx.x * 64;

    // stage x (fp32 -> bf16), swizzle (row&7)<<4 on 16B chunks
    #pragma unroll
    for (int ii = 0; ii < 4; ++ii) {
        int c = threadIdx.x + 256 * ii;          // [0,1024): (row, k8)
        int r = c >> 4, k8 = c & 15;
        int srcrow = row0 + r; if (srcrow >= N) srcrow = N - 1;
        const float4* gp = (const float4*)(x + (size_t)srcrow * 128 + k8 * 8);
        float4 v0 = gp[0], v1 = gp[1];
        bf16x8 p;
        p[0] = (short)f2bf(v0.x); p[1] = (short)f2bf(v0.y);
        p[2] = (short)f2bf(v0.z); p[3] = (short)f2bf(v0.w);
        p[4] = (short)f2bf(v1.x); p[5] = (short)f2bf(v1.y);
        p[6] = (short)f2bf(v1.z); p[7] = (short)f2bf(v1.w);
        *(bf16x8*)((char*)xs_s + r * 256 + ((k8 * 16) ^ ((r & 7) << 4))) = p;
    }
    #pragma unroll
    for (int ii = 0; ii < 9; ++ii)
        ((bf16x8*)wl_s)[threadIdx.x + 256 * ii] = wfrag[threadIdx.x + 256 * ii];
    __syncthreads();
    mfma_compute_store(xs_s, wl_s, row0, N, b0, o0, nullptr, dA0, dB0, cd);

    __syncthreads();
    #pragma unroll
    for (int ii = 0; ii < 9; ++ii)
        ((bf16x8*)wl_s)[threadIdx.x + 256 * ii] = wfrag[2304 + threadIdx.x + 256 * ii];
    __syncthreads();
    mfma_compute_store(xs_s, wl_s, row0, N, b1, nullptr, o1, dA1, nullptr, cd + 8);

    __syncthreads();
    #pragma unroll
    for (int ii = 0; ii < 9; ++ii)
        ((bf16x8*)wl_s)[threadIdx.x + 256 * ii] = wfrag[2 * 2304 + threadIdx.x + 256 * ii];
    __syncthreads();
    mfma_compute_store(xs_s, wl_s, row0, N, b2, nullptr, o2, dA2, nullptr, cd + 16);
}

// ---------- zero fill ----------
__global__ __launch_bounds__(256) void zero_kernel(int* __restrict__ p, int n) {
    int i = blockIdx.x * 256 + threadIdx.x;
    if (i < n) p[i] = 0;
}

// ---------- CSR build: degree count ----------
__global__ __launch_bounds__(256) void count_kernel(Ptr4i dsts, int* __restrict__ deg, int stride, int E) {
    int i = blockIdx.x * 256 + threadIdx.x;
    if (i >= E) return;
    int r = blockIdx.y;
    const int* dst = (r == 0) ? dsts.p0 : (r == 1) ? dsts.p1 : (r == 2) ? dsts.p2 : dsts.p3;
    atomicAdd(deg + (size_t)r * stride + dst[i], 1);
}

// ---------- parallel scan stage 1 ----------
__global__ __launch_bounds__(256) void scan_partial_kernel(
    const int* __restrict__ deg, int stride, int4 Ns, int* __restrict__ blksum, int nblk)
{
    int r = blockIdx.y;
    int N = (r == 0) ? Ns.x : (r == 1) ? Ns.y : (r == 2) ? Ns.z : Ns.w;
    const int* dg = deg + (size_t)r * stride;
    int base = blockIdx.x * 4096 + threadIdx.x * 16;
    int s = 0;
    #pragma unroll 4
    for (int i = 0; i < 16; ++i) {
        int idx = base + i;
        if (idx < N) s += dg[idx];
    }
    #pragma unroll
    for (int off = 1; off < 64; off <<= 1) s += __shfl_xor(s, off, 64);
    __shared__ int wsum[4];
    if ((threadIdx.x & 63) == 0) wsum[threadIdx.x >> 6] = s;
    __syncthreads();
    if (threadIdx.x == 0)
        blksum[(size_t)r * nblk + blockIdx.x] = wsum[0] + wsum[1] + wsum[2] + wsum[3];
}

// ---------- parallel scan stage 2 ----------
__global__ __launch_bounds__(64) void scan_blksum_kernel(int* __restrict__ blksum, int nblk) {
    int r = threadIdx.x;
    if (r >= 4) return;
    int* bs = blksum + (size_t)r * nblk;
    int run = 0;
    for (int i = 0; i < nblk; ++i) { int v = bs[i]; bs[i] = run; run += v; }
}

// ---------- parallel scan stage 3 ----------
__global__ __launch_bounds__(256) void scan_write_kernel(
    const int* __restrict__ deg, const int* __restrict__ blksum, int stride, int4 Ns, int nblk,
    int* __restrict__ start, int* __restrict__ pos)
{
    int r = blockIdx.y;
    int N = (r == 0) ? Ns.x : (r == 1) ? Ns.y : (r == 2) ? Ns.z : Ns.w;
    const int* dg = deg + (size_t)r * stride;
    int base = blockIdx.x * 4096 + threadIdx.x * 16;
    int vals[16];
    int s = 0;
    #pragma unroll 4
    for (int i = 0; i < 16; ++i) {
        int idx = base + i;
        vals[i] = (idx < N) ? dg[idx] : 0;
        s += vals[i];
    }
    __shared__ int sums[256];
    sums[threadIdx.x] = s;
    __syncthreads();
    #pragma unroll
    for (int off = 1; off < 256; off <<= 1) {
        int y = (threadIdx.x >= off) ? sums[threadIdx.x - off] : 0;
        __syncthreads();
        sums[threadIdx.x] += y;
        __syncthreads();
    }
    int run = sums[threadIdx.x] - s + blksum[(size_t)r * nblk + blockIdx.x];
    int* st = start + (size_t)r * stride;
    int* ps = pos + (size_t)r * stride;
    #pragma unroll 4
    for (int i = 0; i < 16; ++i) {
        int idx = base + i;
        if (idx < N) { st[idx] = run; ps[idx] = run; run += vals[i]; }
    }
}

// ---------- CSR build: scatter SRC node ids ----------
__global__ __launch_bounds__(256) void scatter_kernel(Ptr4i dsts, Ptr4i srcs, int* __restrict__ pos,
                                                      int stride, int* __restrict__ csrc, int E) {
    int i = blockIdx.x * 256 + threadIdx.x;
    if (i >= E) return;
    int r = blockIdx.y;
    const int* dst = (r == 0) ? dsts.p0 : (r == 1) ? dsts.p1 : (r == 2) ? dsts.p2 : dsts.p3;
    const int* src = (r == 0) ? srcs.p0 : (r == 1) ? srcs.p1 : (r == 2) ? srcs.p2 : srcs.p3;
    int p = atomicAdd(pos + (size_t)r * stride + dst[i], 1);
    csrc[(size_t)r * E + p] = src[i];
}

// ---------- per-dst fused GAT: single-pass no-max softmax, bf16 gather, 2 edges/wave-iter ----------
__global__ __launch_bounds__(256) void gat_node_kernel(
    float* __restrict__ out, int Nd,
    const int* __restrict__ start0, const int* __restrict__ deg0, const int* __restrict__ csrc0,
    const unsigned short* __restrict__ Wh0, const float* __restrict__ es0, const float* __restrict__ ed0,
    const int* __restrict__ start1, const int* __restrict__ deg1, const int* __restrict__ csrc1,
    const unsigned short* __restrict__ Wh1, const float* __restrict__ es1, const float* __restrict__ ed1)
{
    int gid = blockIdx.x * 256 + threadIdx.x;
    int d = gid >> 6;
    if (d >= Nd) return;
    int lane = threadIdx.x & 63;
    int half = lane >> 5;
    int l    = lane & 31;
    int h    = l >> 3;

    float4 acc = ((const float4*)(out + (size_t)d * 128))[l];   // self term

    #pragma unroll
    for (int rel = 0; rel < 2; ++rel) {
        const int* start = rel ? start1 : start0;
        const int* deg   = rel ? deg1   : deg0;
        const int* csrc  = rel ? csrc1  : csrc0;
        const unsigned short* Wh = rel ? Wh1 : Wh0;
        const float* es  = rel ? es1 : es0;
        const float* ed  = rel ? ed1 : ed0;

        int st = start[d];
        int n  = deg[d];
        if (n == 0) continue;
        float edv = ed[(size_t)d * 4 + h];
        float sum = 0.f;
        float am0 = 0.f, am1 = 0.f, am2 = 0.f, am3 = 0.f;
        for (int j = half; j < n; j += 2) {
            int s = csrc[st + j];
            float p = __expf(leakyf(es[(size_t)s * 4 + h] + edv));
            ushort4 w = ((const ushort4*)(Wh + (size_t)s * 128))[l];
            sum += p;
            am0 += p * bf2f(w.x); am1 += p * bf2f(w.y);
            am2 += p * bf2f(w.z); am3 += p * bf2f(w.w);
        }
        sum += __shfl_xor(sum, 32, 64);
        am0 += __shfl_xor(am0, 32, 64);
        am1 += __shfl_xor(am1, 32, 64);
        am2 += __shfl_xor(am2, 32, 64);
        am3 += __shfl_xor(am3, 32, 64);
        float inv = 1.0f / sum;
        acc.x += am0 * inv; acc.y += am1 * inv;
        acc.z += am2 * inv; acc.w += am3 * inv;
    }
    if (lane < 32) {
        acc.x = fmaxf(acc.x, 0.f); acc.y = fmaxf(acc.y, 0.f);
        acc.z = fmaxf(acc.z, 0.f); acc.w = fmaxf(acc.w, 0.f);
        ((float4*)(out + (size_t)d * 128))[l] = acc;
    }
}

extern "C" void kernel_launch(void* const* d_in, const int* in_sizes, int n_in,
                              void* d_out, int out_size, void* d_ws, size_t ws_size,
                              hipStream_t stream)
{
    const float* feat_P = (const float*)d_in[0];
    const float* feat_A = (const float*)d_in[1];
    const int* src_p2p = (const int*)d_in[2];
    const int* dst_p2p = (const int*)d_in[3];
    const int* src_p2a = (const int*)d_in[4];
    const int* dst_p2a = (const int*)d_in[5];
    const int* src_a2p = (const int*)d_in[6];
    const int* dst_a2p = (const int*)d_in[7];
    const int* src_a2a = (const int*)d_in[8];
    const int* dst_a2a = (const int*)d_in[9];
    const float* W_P   = (const float*)d_in[10]; const float* b_P   = (const float*)d_in[11];
    const float* W_A   = (const float*)d_in[12]; const float* b_A   = (const float*)d_in[13];
    const float* W_p2p = (const float*)d_in[14]; const float* b_p2p = (const float*)d_in[15];
    const float* W_p2a = (const float*)d_in[16]; const float* b_p2a = (const float*)d_in[17];
    const float* W_a2p = (const float*)d_in[18]; const float* b_a2p = (const float*)d_in[19];
    const float* W_a2a = (const float*)d_in[20]; const float* b_a2a = (const float*)d_in[21];
    const float* att_p2p_src = (const float*)d_in[22];
    const float* att_p2p_dst = (const float*)d_in[23];
    const float* att_p2a_src = (const float*)d_in[24];
    const float* att_p2a_dst = (const float*)d_in[25];
    const float* att_a2p_src = (const float*)d_in[26];
    const float* att_a2p_dst = (const float*)d_in[27];
    const float* att_a2a_src = (const float*)d_in[28];
    const float* att_a2a_dst = (const float*)d_in[29];

    const int NP = in_sizes[0] / 128;
    const int NA = in_sizes[1] / 128;
    const int E  = in_sizes[2];
    const int stride = (NP > NA) ? NP : NA;
    const int nblk = (stride + 4095) / 4096;

    float* outP = (float*)d_out;
    float* outA = (float*)d_out + (size_t)NP * 128;

    char* ws = (char*)d_ws;
    size_t off = 0;
    auto alloc = [&](size_t bytes) -> void* {
        void* p = ws + off;
        off += (bytes + 255) & ~(size_t)255;
        return p;
    };
    unsigned short* Whp2p = (unsigned short*)alloc((size_t)NP * 128 * 2);
    unsigned short* Whp2a = (unsigned short*)alloc((size_t)NP * 128 * 2);
    unsigned short* Wha2p = (unsigned short*)alloc((size_t)NA * 128 * 2);
    unsigned short* Wha2a = (unsigned short*)alloc((size_t)NA * 128 * 2);
    float* es_p2p = (float*)alloc((size_t)NP * 16);
    float* es_p2a = (float*)alloc((size_t)NP * 16);
    float* es_a2p = (float*)alloc((size_t)NA * 16);
    float* es_a2a = (float*)alloc((size_t)NA * 16);
    float* ed_p2p = (float*)alloc((size_t)NP * 16);
    float* ed_a2p = (float*)alloc((size_t)NP * 16);
    float* ed_p2a = (float*)alloc((size_t)NA * 16);
    float* ed_a2a = (float*)alloc((size_t)NA * 16);
    int* deg    = (int*)alloc((size_t)4 * stride * 4);
    int* start  = (int*)alloc((size_t)4 * stride * 4);
    int* pos    = (int*)alloc((size_t)4 * stride * 4);
    int* csrc   = (int*)alloc((size_t)4 * E * 4);
    int* blksum = (int*)alloc((size_t)4 * nblk * 4);
    bf16x8* wfrag = (bf16x8*)alloc((size_t)6 * 2304 * 16);
    float* cd     = (float*)alloc((size_t)6 * 8 * 4);

    // relation order: 0=p2p(dst P), 1=a2p(dst P), 2=p2a(dst A), 3=a2a(dst A)
    Ptr4i dsts = {dst_p2p, dst_a2p, dst_p2a, dst_a2a};
    Ptr4i srcs = {src_p2p, src_a2p, src_p2a, src_a2a};
    int4 Ns = make_int4(NP, NP, NA, NA);

    // ---- 0) prep fragment-linear bf16 weights + folded dot cols ----
    {
        PrepM m0 = {W_P,   b_P,   att_p2p_dst, att_a2p_dst};  // self P: ed_p2p, ed_a2p
        PrepM m1 = {W_p2p, b_p2p, att_p2p_src, nullptr};      // es_p2p
        PrepM m2 = {W_p2a, b_p2a, att_p2a_src, nullptr};      // es_p2a
        PrepM m3 = {W_A,   b_A,   att_p2a_dst, att_a2a_dst};  // self A: ed_p2a, ed_a2a
        PrepM m4 = {W_a2p, b_a2p, att_a2p_src, nullptr};      // es_a2p
        PrepM m5 = {W_a2a, b_a2a, att_a2a_src, nullptr};      // es_a2a
        prep_kernel<<<dim3(6, 4), 256, 0, stream>>>(m0, m1, m2, m3, m4, m5, wfrag, cd);
    }

    // ---- 1) fused MFMA linears (self into d_out fp32; relations bf16; dots folded) ----
    lin3_mfma_kernel<<<(NP + 63) / 64, 256, 0, stream>>>(feat_P, NP,
        wfrag, cd,
        b_P,   outP,  ed_p2p, ed_a2p,
        b_p2p, Whp2p, es_p2p,
        b_p2a, Whp2a, es_p2a);
    lin3_mfma_kernel<<<(NA + 63) / 64, 256, 0, stream>>>(feat_A, NA,
        wfrag + (size_t)3 * 2304, cd + 24,
        b_A,   outA,  ed_p2a, ed_a2a,
        b_a2p, Wha2p, es_a2p,
        b_a2a, Wha2a, es_a2a);

    // ---- 2) CSR build ----
    zero_kernel<<<(4 * stride + 255) / 256, 256, 0, stream>>>(deg, 4 * stride);
    {
        dim3 ge((E + 255) / 256, 4);
        dim3 gs(nblk, 4);
        count_kernel<<<ge, 256, 0, stream>>>(dsts, deg, stride, E);
        scan_partial_kernel<<<gs, 256, 0, stream>>>(deg, stride, Ns, blksum, nblk);
        scan_blksum_kernel<<<1, 64, 0, stream>>>(blksum, nblk);
        scan_write_kernel<<<gs, 256, 0, stream>>>(deg, blksum, stride, Ns, nblk, start, pos);
        scatter_kernel<<<ge, 256, 0, stream>>>(dsts, srcs, pos, stride, csrc, E);
    }

    // ---- 3) fused per-dst aggregation (+self +relu) ----
    gat_node_kernel<<<(NP * 64 + 255) / 256, 256, 0, stream>>>(outP, NP,
        start + 0 * (size_t)stride, deg + 0 * (size_t)stride, csrc + 0 * (size_t)E, Whp2p, es_p2p, ed_p2p,
        start + 1 * (size_t)stride, deg + 1 * (size_t)stride, csrc + 1 * (size_t)E, Wha2p, es_a2p, ed_a2p);
    gat_node_kernel<<<(NA * 64 + 255) / 256, 256, 0, stream>>>(outA, NA,
        start + 2 * (size_t)stride, deg + 2 * (size_t)stride, csrc + 2 * (size_t)E, Whp2a, es_p2a, ed_p2a,
        start + 3 * (size_t)stride, deg + 3 * (size_t)stride, csrc + 3 * (size_t)E, Wha2a, es_a2a, ed_a2a);
}

// Round 6
// 374.570 us; speedup vs baseline: 7.8164x; 1.5613x over previous
//
#include <hip/hip_runtime.h>
#include <float.h>

#define ALPHA 0.2f
__device__ __forceinline__ float leakyf(float x) { return x > 0.0f ? x : ALPHA * x; }

__device__ __forceinline__ float bf2f(unsigned short u) {
    return __uint_as_float((unsigned)u << 16);
}
__device__ __forceinline__ unsigned short f2bf(float f) {
    unsigned u = __float_as_uint(f);
    return (unsigned short)((u + 0x7FFFu + ((u >> 16) & 1u)) >> 16);
}
__device__ __forceinline__ float bflo(unsigned u) { return __uint_as_float(u << 16); }
__device__ __forceinline__ float bfhi(unsigned u) { return __uint_as_float(u & 0xFFFF0000u); }

typedef short bf16x8 __attribute__((ext_vector_type(8)));
typedef float f32x4 __attribute__((ext_vector_type(4)));

struct Ptr4i { const int* p0; const int* p1; const int* p2; const int* p3; };
struct PrepM { const float* W; const float* b; const float* attA; const float* attB; };

// ---------- prep: build fragment-linear bf16 W (+ folded attention-dot cols) ----------
__global__ __launch_bounds__(256) void prep_kernel(
    PrepM m0, PrepM m1, PrepM m2, PrepM m3, PrepM m4, PrepM m5,
    bf16x8* __restrict__ wfrag, float* __restrict__ cd)
{
    int mi = blockIdx.x;
    PrepM mm = (mi == 0) ? m0 : (mi == 1) ? m1 : (mi == 2) ? m2 :
               (mi == 3) ? m3 : (mi == 4) ? m4 : m5;
    int part = blockIdx.y;
    for (int ii = 0; ii < 3; ++ii) {
        int c = part * 576 + threadIdx.x + 256 * ii;
        if (c >= part * 576 + 576) continue;
        int t = c >> 8;
        int kstep = (c >> 6) & 3;
        int l = c & 63;
        int k0 = kstep * 32 + (l >> 4) * 8;
        bf16x8 out;
        if (t < 8) {
            int col = t * 16 + (l & 15);
            #pragma unroll
            for (int j = 0; j < 8; ++j)
                out[j] = (short)f2bf(mm.W[(size_t)(k0 + j) * 128 + col]);
        } else {
            int cl = l & 15;
            const float* att = nullptr; int h = 0;
            if (cl < 4 && mm.attA) { att = mm.attA; h = cl; }
            else if (cl >= 4 && cl < 8 && mm.attB) { att = mm.attB; h = cl - 4; }
            #pragma unroll
            for (int j = 0; j < 8; ++j) {
                float s = 0.f;
                if (att) {
                    const float* wrow = mm.W + (size_t)(k0 + j) * 128 + h * 32;
                    for (int d = 0; d < 32; ++d) s += wrow[d] * att[h * 32 + d];
                }
                out[j] = (short)f2bf(s);
            }
        }
        wfrag[(size_t)mi * 2304 + c] = out;
    }
    if (part == 0 && threadIdx.x < 8) {
        int cl = threadIdx.x;
        float s = 0.f;
        const float* att = nullptr; int h = 0;
        if (cl < 4 && mm.attA) { att = mm.attA; h = cl; }
        else if (cl >= 4 && mm.attB) { att = mm.attB; h = cl - 4; }
        if (att) for (int d = 0; d < 32; ++d) s += mm.b[h * 32 + d] * att[h * 32 + d];
        cd[mi * 8 + cl] = s;
    }
}

// ---------- MFMA compute + epilogue for one matrix ----------
__device__ __forceinline__ void mfma_compute_store(
    const short* xs_s, const short* wl_s, int row0, int N,
    const float* __restrict__ b, float* __restrict__ o32, unsigned short* __restrict__ o16,
    float* __restrict__ dotA, float* __restrict__ dotB, const float* __restrict__ cd)
{
    int l = threadIdx.x & 63, w = threadIdx.x >> 6;
    int cl = l & 15, gq = l >> 4;
    f32x4 acc[9];
    #pragma unroll
    for (int t = 0; t < 9; ++t) acc[t] = (f32x4){0.f, 0.f, 0.f, 0.f};
    int arow = w * 16 + cl;
    #pragma unroll
    for (int ks = 0; ks < 4; ++ks) {
        int k8 = ks * 4 + gq;
        bf16x8 a = *(const bf16x8*)((const char*)xs_s + arow * 256 + ((k8 * 16) ^ ((arow & 7) << 4)));
        #pragma unroll
        for (int t = 0; t < 9; ++t) {
            bf16x8 bf = *(const bf16x8*)((const char*)wl_s + ((t * 4 + ks) * 64 + l) * 16);
            acc[t] = __builtin_amdgcn_mfma_f32_16x16x32_bf16(a, bf, acc[t], 0, 0, 0);
        }
    }
    int rbase = row0 + w * 16 + gq * 4;
    #pragma unroll
    for (int t = 0; t < 8; ++t) {
        int col = t * 16 + cl;
        float bias = b[col];
        #pragma unroll
        for (int j = 0; j < 4; ++j) {
            int row = rbase + j;
            if (row < N) {
                float v = acc[t][j] + bias;
                if (o32) o32[(size_t)row * 128 + col] = v;
                else     o16[(size_t)row * 128 + col] = f2bf(v);
            }
        }
    }
    if (cl < 8) {
        float cdv = cd[cl];
        float* dp = (cl < 4) ? dotA : dotB;
        int h = cl & 3;
        if (dp) {
            #pragma unroll
            for (int j = 0; j < 4; ++j) {
                int row = rbase + j;
                if (row < N) dp[(size_t)row * 4 + h] = acc[8][j] + cdv;
            }
        }
    }
}

// ---------- fused 3-matrix MFMA linear ----------
__global__ __launch_bounds__(256) void lin3_mfma_kernel(
    const float* __restrict__ x, int N,
    const bf16x8* __restrict__ wfrag, const float* __restrict__ cd,
    const float* __restrict__ b0, float* __restrict__ o0, float* __restrict__ dA0, float* __restrict__ dB0,
    const float* __restrict__ b1, unsigned short* __restrict__ o1, float* __restrict__ dA1,
    const float* __restrict__ b2, unsigned short* __restrict__ o2, float* __restrict__ dA2)
{
    __shared__ short xs_s[64 * 128];
    __shared__ short wl_s[2304 * 8];
    const int row0 = blockIdx.x * 64;

    #pragma unroll
    for (int ii = 0; ii < 4; ++ii) {
        int c = threadIdx.x + 256 * ii;
        int r = c >> 4, k8 = c & 15;
        int srcrow = row0 + r; if (srcrow >= N) srcrow = N - 1;
        const float4* gp = (const float4*)(x + (size_t)srcrow * 128 + k8 * 8);
        float4 v0 = gp[0], v1 = gp[1];
        bf16x8 p;
        p[0] = (short)f2bf(v0.x); p[1] = (short)f2bf(v0.y);
        p[2] = (short)f2bf(v0.z); p[3] = (short)f2bf(v0.w);
        p[4] = (short)f2bf(v1.x); p[5] = (short)f2bf(v1.y);
        p[6] = (short)f2bf(v1.z); p[7] = (short)f2bf(v1.w);
        *(bf16x8*)((char*)xs_s + r * 256 + ((k8 * 16) ^ ((r & 7) << 4))) = p;
    }
    #pragma unroll
    for (int ii = 0; ii < 9; ++ii)
        ((bf16x8*)wl_s)[threadIdx.x + 256 * ii] = wfrag[threadIdx.x + 256 * ii];
    __syncthreads();
    mfma_compute_store(xs_s, wl_s, row0, N, b0, o0, nullptr, dA0, dB0, cd);

    __syncthreads();
    #pragma unroll
    for (int ii = 0; ii < 9; ++ii)
        ((bf16x8*)wl_s)[threadIdx.x + 256 * ii] = wfrag[2304 + threadIdx.x + 256 * ii];
    __syncthreads();
    mfma_compute_store(xs_s, wl_s, row0, N, b1, nullptr, o1, dA1, nullptr, cd + 8);

    __syncthreads();
    #pragma unroll
    for (int ii = 0; ii < 9; ++ii)
        ((bf16x8*)wl_s)[threadIdx.x + 256 * ii] = wfrag[2 * 2304 + threadIdx.x + 256 * ii];
    __syncthreads();
    mfma_compute_store(xs_s, wl_s, row0, N, b2, nullptr, o2, dA2, nullptr, cd + 16);
}

// ---------- zero fill ----------
__global__ __launch_bounds__(256) void zero_kernel(int* __restrict__ p, int n) {
    int i = blockIdx.x * 256 + threadIdx.x;
    if (i < n) p[i] = 0;
}

// ================= bucketed CSR build (buckets of 1024 dsts) =================

// ---- pass A1: per-bucket edge counts ----
__global__ __launch_bounds__(256) void binA_count_kernel(Ptr4i dsts, int* __restrict__ bcnt,
                                                         int nbkMax, int E)
{
    __shared__ int lh[128];
    if (threadIdx.x < 128) lh[threadIdx.x] = 0;
    __syncthreads();
    int r = blockIdx.y;
    const int* dst = (r == 0) ? dsts.p0 : (r == 1) ? dsts.p1 : (r == 2) ? dsts.p2 : dsts.p3;
    int base = blockIdx.x * 4096;
    #pragma unroll 4
    for (int ii = 0; ii < 16; ++ii) {
        int i = base + threadIdx.x + 256 * ii;
        if (i < E) atomicAdd(&lh[dst[i] >> 10], 1);
    }
    __syncthreads();
    if (threadIdx.x < nbkMax) {
        int v = lh[threadIdx.x];
        if (v) atomicAdd(&bcnt[r * nbkMax + threadIdx.x], v);
    }
}

// ---- tiny scan: per-relation exclusive prefix of bucket counts ----
__global__ __launch_bounds__(64) void bin_scan_kernel(const int* __restrict__ bcnt,
                                                      int* __restrict__ bbase,
                                                      int* __restrict__ gwptr, int nbkMax)
{
    int r = threadIdx.x;
    if (r >= 4) return;
    int run = 0;
    for (int b = 0; b < nbkMax; ++b) {
        int v = bcnt[r * nbkMax + b];
        bbase[r * nbkMax + b] = run;
        gwptr[r * nbkMax + b] = run;
        run += v;
    }
}

// ---- pass A2: LDS-binned scatter into bucket-ordered packed array ----
// packed = (src << 10) | (dst & 1023)
__global__ __launch_bounds__(256) void binA_scatter_kernel(Ptr4i dsts, Ptr4i srcs,
    int* __restrict__ gwptr, unsigned* __restrict__ packed, int nbkMax, int E)
{
    __shared__ int lh[128], loff[128], lptr[128], gb[128];
    __shared__ unsigned stg[4096];
    __shared__ unsigned short sb[4096];
    if (threadIdx.x < 128) lh[threadIdx.x] = 0;
    __syncthreads();
    int r = blockIdx.y;
    const int* dst = (r == 0) ? dsts.p0 : (r == 1) ? dsts.p1 : (r == 2) ? dsts.p2 : dsts.p3;
    const int* src = (r == 0) ? srcs.p0 : (r == 1) ? srcs.p1 : (r == 2) ? srcs.p2 : srcs.p3;
    int base = blockIdx.x * 4096;
    int d16[16], s16[16];
    #pragma unroll 4
    for (int ii = 0; ii < 16; ++ii) {
        int i = base + threadIdx.x + 256 * ii;
        if (i < E) {
            d16[ii] = dst[i];
            s16[ii] = src[i];
            atomicAdd(&lh[d16[ii] >> 10], 1);
        } else d16[ii] = -1;
    }
    __syncthreads();
    if (threadIdx.x == 0) {
        int run = 0;
        for (int b = 0; b < nbkMax; ++b) { loff[b] = run; lptr[b] = run; run += lh[b]; }
    }
    __syncthreads();
    #pragma unroll 4
    for (int ii = 0; ii < 16; ++ii) {
        if (d16[ii] >= 0) {
            int b = d16[ii] >> 10;
            int p = atomicAdd(&lptr[b], 1);
            stg[p] = ((unsigned)s16[ii] << 10) | (unsigned)(d16[ii] & 1023);
            sb[p] = (unsigned short)b;
        }
    }
    __syncthreads();
    if (threadIdx.x < nbkMax && lh[threadIdx.x])
        gb[threadIdx.x] = atomicAdd(&gwptr[r * nbkMax + threadIdx.x], lh[threadIdx.x]);
    __syncthreads();
    int tot = min(4096, E - base);
    #pragma unroll 4
    for (int ii = 0; ii < 16; ++ii) {
        int p = threadIdx.x + 256 * ii;
        if (p < tot) {
            int b = sb[p];
            packed[(size_t)r * E + gb[b] + (p - loff[b])] = stg[p];
        }
    }
}

// ---- pass B: per-bucket CSR finalize (deg/start/csrc) ----
__global__ __launch_bounds__(256) void binB_build_kernel(
    const unsigned* __restrict__ packed, const int* __restrict__ bcnt, const int* __restrict__ bbase,
    int nbkMax, int4 Ns, int E, int stride,
    int* __restrict__ start, int* __restrict__ deg, int* __restrict__ csrc)
{
    int r = blockIdx.y, b = blockIdx.x;
    int N = (r == 0) ? Ns.x : (r == 1) ? Ns.y : (r == 2) ? Ns.z : Ns.w;
    int dst0 = b << 10;
    if (dst0 >= N) return;
    int cnt  = bcnt[r * nbkMax + b];
    int base = bbase[r * nbkMax + b];
    __shared__ int hist[1024];
    __shared__ int sums[256];
    #pragma unroll
    for (int i = 0; i < 4; ++i) hist[threadIdx.x * 4 + i] = 0;
    __syncthreads();
    const unsigned* pk = packed + (size_t)r * E + base;
    for (int i = threadIdx.x; i < cnt; i += 256)
        atomicAdd(&hist[pk[i] & 1023], 1);
    __syncthreads();
    int v4[4], s = 0;
    #pragma unroll
    for (int i = 0; i < 4; ++i) { v4[i] = hist[threadIdx.x * 4 + i]; s += v4[i]; }
    sums[threadIdx.x] = s;
    __syncthreads();
    #pragma unroll
    for (int off = 1; off < 256; off <<= 1) {
        int y = (threadIdx.x >= off) ? sums[threadIdx.x - off] : 0;
        __syncthreads();
        sums[threadIdx.x] += y;
        __syncthreads();
    }
    int run = sums[threadIdx.x] - s;
    int* st = start + (size_t)r * stride;
    int* dg = deg   + (size_t)r * stride;
    #pragma unroll
    for (int i = 0; i < 4; ++i) {
        int idx = threadIdx.x * 4 + i;
        int d = dst0 + idx;
        if (d < N) { dg[d] = v4[i]; st[d] = base + run; }
        hist[idx] = run;
        run += v4[i];
    }
    __syncthreads();
    int* cs = csrc + (size_t)r * E + base;
    for (int i = threadIdx.x; i < cnt; i += 256) {
        unsigned e = pk[i];
        int p = atomicAdd(&hist[e & 1023], 1);
        cs[p] = (int)(e >> 10);
    }
}

// ---------- per-dst fused GAT: no-max softmax, bf16 gather, 4 edges/wave-iter ----------
__global__ __launch_bounds__(256) void gat_node_kernel(
    float* __restrict__ out, int Nd,
    const int* __restrict__ start0, const int* __restrict__ deg0, const int* __restrict__ csrc0,
    const unsigned short* __restrict__ Wh0, const float* __restrict__ es0, const float* __restrict__ ed0,
    const int* __restrict__ start1, const int* __restrict__ deg1, const int* __restrict__ csrc1,
    const unsigned short* __restrict__ Wh1, const float* __restrict__ es1, const float* __restrict__ ed1)
{
    int gid = blockIdx.x * 256 + threadIdx.x;
    int d = gid >> 6;
    if (d >= Nd) return;
    int lane = threadIdx.x & 63;
    int q = lane >> 4;        // edge slot (4-way)
    int l = lane & 15;        // dim group: dims 8l..8l+7
    int h = l >> 2;           // head

    const float4* orow = (const float4*)(out + (size_t)d * 128);
    float4 A0 = orow[l * 2], A1 = orow[l * 2 + 1];

    #pragma unroll
    for (int rel = 0; rel < 2; ++rel) {
        const int* start = rel ? start1 : start0;
        const int* deg   = rel ? deg1   : deg0;
        const int* csrc  = rel ? csrc1  : csrc0;
        const unsigned short* Wh = rel ? Wh1 : Wh0;
        const float* es  = rel ? es1 : es0;
        const float* ed  = rel ? ed1 : ed0;

        int st = start[d];
        int n  = deg[d];
        if (n == 0) continue;
        float edv = ed[(size_t)d * 4 + h];
        float sum = 0.f;
        float m0 = 0.f, m1 = 0.f, m2 = 0.f, m3 = 0.f;
        float m4 = 0.f, m5 = 0.f, m6 = 0.f, m7 = 0.f;
        for (int j = q; j < n; j += 4) {
            int s = csrc[st + j];
            float p = __expf(leakyf(es[(size_t)s * 4 + h] + edv));
            uint4 w = ((const uint4*)(Wh + (size_t)s * 128))[l];
            sum += p;
            m0 += p * bflo(w.x); m1 += p * bfhi(w.x);
            m2 += p * bflo(w.y); m3 += p * bfhi(w.y);
            m4 += p * bflo(w.z); m5 += p * bfhi(w.z);
            m6 += p * bflo(w.w); m7 += p * bfhi(w.w);
        }
        #pragma unroll
        for (int off = 16; off < 64; off <<= 1) {
            sum += __shfl_xor(sum, off, 64);
            m0 += __shfl_xor(m0, off, 64); m1 += __shfl_xor(m1, off, 64);
            m2 += __shfl_xor(m2, off, 64); m3 += __shfl_xor(m3, off, 64);
            m4 += __shfl_xor(m4, off, 64); m5 += __shfl_xor(m5, off, 64);
            m6 += __shfl_xor(m6, off, 64); m7 += __shfl_xor(m7, off, 64);
        }
        float inv = 1.0f / sum;
        A0.x += m0 * inv; A0.y += m1 * inv; A0.z += m2 * inv; A0.w += m3 * inv;
        A1.x += m4 * inv; A1.y += m5 * inv; A1.z += m6 * inv; A1.w += m7 * inv;
    }
    if (lane < 16) {
        A0.x = fmaxf(A0.x, 0.f); A0.y = fmaxf(A0.y, 0.f);
        A0.z = fmaxf(A0.z, 0.f); A0.w = fmaxf(A0.w, 0.f);
        A1.x = fmaxf(A1.x, 0.f); A1.y = fmaxf(A1.y, 0.f);
        A1.z = fmaxf(A1.z, 0.f); A1.w = fmaxf(A1.w, 0.f);
        float4* ow = (float4*)(out + (size_t)d * 128);
        ow[l * 2] = A0; ow[l * 2 + 1] = A1;
    }
}

extern "C" void kernel_launch(void* const* d_in, const int* in_sizes, int n_in,
                              void* d_out, int out_size, void* d_ws, size_t ws_size,
                              hipStream_t stream)
{
    const float* feat_P = (const float*)d_in[0];
    const float* feat_A = (const float*)d_in[1];
    const int* src_p2p = (const int*)d_in[2];
    const int* dst_p2p = (const int*)d_in[3];
    const int* src_p2a = (const int*)d_in[4];
    const int* dst_p2a = (const int*)d_in[5];
    const int* src_a2p = (const int*)d_in[6];
    const int* dst_a2p = (const int*)d_in[7];
    const int* src_a2a = (const int*)d_in[8];
    const int* dst_a2a = (const int*)d_in[9];
    const float* W_P   = (const float*)d_in[10]; const float* b_P   = (const float*)d_in[11];
    const float* W_A   = (const float*)d_in[12]; const float* b_A   = (const float*)d_in[13];
    const float* W_p2p = (const float*)d_in[14]; const float* b_p2p = (const float*)d_in[15];
    const float* W_p2a = (const float*)d_in[16]; const float* b_p2a = (const float*)d_in[17];
    const float* W_a2p = (const float*)d_in[18]; const float* b_a2p = (const float*)d_in[19];
    const float* W_a2a = (const float*)d_in[20]; const float* b_a2a = (const float*)d_in[21];
    const float* att_p2p_src = (const float*)d_in[22];
    const float* att_p2p_dst = (const float*)d_in[23];
    const float* att_p2a_src = (const float*)d_in[24];
    const float* att_p2a_dst = (const float*)d_in[25];
    const float* att_a2p_src = (const float*)d_in[26];
    const float* att_a2p_dst = (const float*)d_in[27];
    const float* att_a2a_src = (const float*)d_in[28];
    const float* att_a2a_dst = (const float*)d_in[29];

    const int NP = in_sizes[0] / 128;
    const int NA = in_sizes[1] / 128;
    const int E  = in_sizes[2];
    const int stride = (NP > NA) ? NP : NA;
    const int nbkMax = (stride + 1023) >> 10;   // <= 128

    float* outP = (float*)d_out;
    float* outA = (float*)d_out + (size_t)NP * 128;

    char* ws = (char*)d_ws;
    size_t off = 0;
    auto alloc = [&](size_t bytes) -> void* {
        void* p = ws + off;
        off += (bytes + 255) & ~(size_t)255;
        return p;
    };
    unsigned short* Whp2p = (unsigned short*)alloc((size_t)NP * 128 * 2);
    unsigned short* Whp2a = (unsigned short*)alloc((size_t)NP * 128 * 2);
    unsigned short* Wha2p = (unsigned short*)alloc((size_t)NA * 128 * 2);
    unsigned short* Wha2a = (unsigned short*)alloc((size_t)NA * 128 * 2);
    float* es_p2p = (float*)alloc((size_t)NP * 16);
    float* es_p2a = (float*)alloc((size_t)NP * 16);
    float* es_a2p = (float*)alloc((size_t)NA * 16);
    float* es_a2a = (float*)alloc((size_t)NA * 16);
    float* ed_p2p = (float*)alloc((size_t)NP * 16);
    float* ed_a2p = (float*)alloc((size_t)NP * 16);
    float* ed_p2a = (float*)alloc((size_t)NA * 16);
    float* ed_a2a = (float*)alloc((size_t)NA * 16);
    int* deg    = (int*)alloc((size_t)4 * stride * 4);
    int* start  = (int*)alloc((size_t)4 * stride * 4);
    int* csrc   = (int*)alloc((size_t)4 * E * 4);
    unsigned* packed = (unsigned*)alloc((size_t)4 * E * 4);
    int* bcnt   = (int*)alloc((size_t)4 * nbkMax * 4);
    int* bbase  = (int*)alloc((size_t)4 * nbkMax * 4);
    int* gwptr  = (int*)alloc((size_t)4 * nbkMax * 4);
    bf16x8* wfrag = (bf16x8*)alloc((size_t)6 * 2304 * 16);
    float* cd     = (float*)alloc((size_t)6 * 8 * 4);

    // relation order: 0=p2p(dst P), 1=a2p(dst P), 2=p2a(dst A), 3=a2a(dst A)
    Ptr4i dsts = {dst_p2p, dst_a2p, dst_p2a, dst_a2a};
    Ptr4i srcs = {src_p2p, src_a2p, src_p2a, src_a2a};
    int4 Ns = make_int4(NP, NP, NA, NA);

    // ---- 0) prep weights ----
    {
        PrepM m0 = {W_P,   b_P,   att_p2p_dst, att_a2p_dst};
        PrepM m1 = {W_p2p, b_p2p, att_p2p_src, nullptr};
        PrepM m2 = {W_p2a, b_p2a, att_p2a_src, nullptr};
        PrepM m3 = {W_A,   b_A,   att_p2a_dst, att_a2a_dst};
        PrepM m4 = {W_a2p, b_a2p, att_a2p_src, nullptr};
        PrepM m5 = {W_a2a, b_a2a, att_a2a_src, nullptr};
        prep_kernel<<<dim3(6, 4), 256, 0, stream>>>(m0, m1, m2, m3, m4, m5, wfrag, cd);
    }

    // ---- 1) fused MFMA linears ----
    lin3_mfma_kernel<<<(NP + 63) / 64, 256, 0, stream>>>(feat_P, NP,
        wfrag, cd,
        b_P,   outP,  ed_p2p, ed_a2p,
        b_p2p, Whp2p, es_p2p,
        b_p2a, Whp2a, es_p2a);
    lin3_mfma_kernel<<<(NA + 63) / 64, 256, 0, stream>>>(feat_A, NA,
        wfrag + (size_t)3 * 2304, cd + 24,
        b_A,   outA,  ed_p2a, ed_a2a,
        b_a2p, Wha2p, es_a2p,
        b_a2a, Wha2a, es_a2a);

    // ---- 2) bucketed CSR build ----
    zero_kernel<<<(4 * nbkMax + 255) / 256, 256, 0, stream>>>(bcnt, 4 * nbkMax);
    {
        dim3 gA((E + 4095) / 4096, 4);
        binA_count_kernel<<<gA, 256, 0, stream>>>(dsts, bcnt, nbkMax, E);
        bin_scan_kernel<<<1, 64, 0, stream>>>(bcnt, bbase, gwptr, nbkMax);
        binA_scatter_kernel<<<gA, 256, 0, stream>>>(dsts, srcs, gwptr, packed, nbkMax, E);
        binB_build_kernel<<<dim3(nbkMax, 4), 256, 0, stream>>>(packed, bcnt, bbase,
            nbkMax, Ns, E, stride, start, deg, csrc);
    }

    // ---- 3) fused per-dst aggregation (+self +relu) ----
    gat_node_kernel<<<(NP * 64 + 255) / 256, 256, 0, stream>>>(outP, NP,
        start + 0 * (size_t)stride, deg + 0 * (size_t)stride, csrc + 0 * (size_t)E, Whp2p, es_p2p, ed_p2p,
        start + 1 * (size_t)stride, deg + 1 * (size_t)stride, csrc + 1 * (size_t)E, Wha2p, es_a2p, ed_a2p);
    gat_node_kernel<<<(NA * 64 + 255) / 256, 256, 0, stream>>>(outA, NA,
        start + 2 * (size_t)stride, deg + 2 * (size_t)stride, csrc + 2 * (size_t)E, Whp2a, es_p2a, ed_p2a,
        start + 3 * (size_t)stride, deg + 3 * (size_t)stride, csrc + 3 * (size_t)E, Wha2a, es_a2a, ed_a2a);
}

// Round 8
// 336.672 us; speedup vs baseline: 8.6963x; 1.1126x over previous
//
#include <hip/hip_runtime.h>
#include <float.h>

#define ALPHA 0.2f
__device__ __forceinline__ float leakyf(float x) { return x > 0.0f ? x : ALPHA * x; }

__device__ __forceinline__ unsigned short f2bf(float f) {
    unsigned u = __float_as_uint(f);
    return (unsigned short)((u + 0x7FFFu + ((u >> 16) & 1u)) >> 16);
}
__device__ __forceinline__ float bflo(unsigned u) { return __uint_as_float(u << 16); }
__device__ __forceinline__ float bfhi(unsigned u) { return __uint_as_float(u & 0xFFFF0000u); }

typedef short bf16x8 __attribute__((ext_vector_type(8)));
typedef float f32x4 __attribute__((ext_vector_type(4)));

struct Ptr4i { const int* p0; const int* p1; const int* p2; const int* p3; };
struct PrepM { const float* W; const float* b; const float* attA; const float* attB; };

// ---------- prep: fragment-linear bf16 W (+ folded attention-dot cols) + bcnt zero ----------
__global__ __launch_bounds__(256) void prep_kernel(
    PrepM m0, PrepM m1, PrepM m2, PrepM m3, PrepM m4, PrepM m5,
    bf16x8* __restrict__ wfrag, float* __restrict__ cd,
    int* __restrict__ bcnt, int nz)
{
    int mi = blockIdx.x;
    PrepM mm = (mi == 0) ? m0 : (mi == 1) ? m1 : (mi == 2) ? m2 :
               (mi == 3) ? m3 : (mi == 4) ? m4 : m5;
    int part = blockIdx.y;
    if (mi == 0 && part == 0) {
        for (int i = threadIdx.x; i < nz; i += 256) bcnt[i] = 0;
    }
    for (int ii = 0; ii < 3; ++ii) {
        int c = part * 576 + threadIdx.x + 256 * ii;
        if (c >= part * 576 + 576) continue;
        int t = c >> 8;
        int kstep = (c >> 6) & 3;
        int l = c & 63;
        int k0 = kstep * 32 + (l >> 4) * 8;
        bf16x8 out;
        if (t < 8) {
            int col = t * 16 + (l & 15);
            #pragma unroll
            for (int j = 0; j < 8; ++j)
                out[j] = (short)f2bf(mm.W[(size_t)(k0 + j) * 128 + col]);
        } else {
            int cl = l & 15;
            const float* att = nullptr; int h = 0;
            if (cl < 4 && mm.attA) { att = mm.attA; h = cl; }
            else if (cl >= 4 && cl < 8 && mm.attB) { att = mm.attB; h = cl - 4; }
            #pragma unroll
            for (int j = 0; j < 8; ++j) {
                float s = 0.f;
                if (att) {
                    const float* wrow = mm.W + (size_t)(k0 + j) * 128 + h * 32;
                    for (int d = 0; d < 32; ++d) s += wrow[d] * att[h * 32 + d];
                }
                out[j] = (short)f2bf(s);
            }
        }
        wfrag[(size_t)mi * 2304 + c] = out;
    }
    if (part == 0 && threadIdx.x < 8) {
        int cl = threadIdx.x;
        float s = 0.f;
        const float* att = nullptr; int h = 0;
        if (cl < 4 && mm.attA) { att = mm.attA; h = cl; }
        else if (cl >= 4 && mm.attB) { att = mm.attB; h = cl - 4; }
        if (att) for (int d = 0; d < 32; ++d) s += mm.b[h * 32 + d] * att[h * 32 + d];
        cd[mi * 8 + cl] = s;
    }
}

// ---------- MFMA compute + epilogue for one matrix ----------
__device__ __forceinline__ void mfma_compute_store(
    const short* xs_s, const short* wl_s, int row0, int N,
    const float* __restrict__ b, float* __restrict__ o32, unsigned short* __restrict__ o16,
    float* __restrict__ dotA, float* __restrict__ dotB, const float* __restrict__ cd)
{
    int l = threadIdx.x & 63, w = threadIdx.x >> 6;
    int cl = l & 15, gq = l >> 4;
    f32x4 acc[9];
    #pragma unroll
    for (int t = 0; t < 9; ++t) acc[t] = (f32x4){0.f, 0.f, 0.f, 0.f};
    int arow = w * 16 + cl;
    #pragma unroll
    for (int ks = 0; ks < 4; ++ks) {
        int k8 = ks * 4 + gq;
        bf16x8 a = *(const bf16x8*)((const char*)xs_s + arow * 256 + ((k8 * 16) ^ ((arow & 7) << 4)));
        #pragma unroll
        for (int t = 0; t < 9; ++t) {
            bf16x8 bf = *(const bf16x8*)((const char*)wl_s + ((t * 4 + ks) * 64 + l) * 16);
            acc[t] = __builtin_amdgcn_mfma_f32_16x16x32_bf16(a, bf, acc[t], 0, 0, 0);
        }
    }
    int rbase = row0 + w * 16 + gq * 4;
    #pragma unroll
    for (int t = 0; t < 8; ++t) {
        int col = t * 16 + cl;
        float bias = b[col];
        #pragma unroll
        for (int j = 0; j < 4; ++j) {
            int row = rbase + j;
            if (row < N) {
                float v = acc[t][j] + bias;
                if (o32) o32[(size_t)row * 128 + col] = v;
                else     o16[(size_t)row * 128 + col] = f2bf(v);
            }
        }
    }
    if (cl < 8) {
        float cdv = cd[cl];
        float* dp = (cl < 4) ? dotA : dotB;
        int h = cl & 3;
        if (dp) {
            #pragma unroll
            for (int j = 0; j < 4; ++j) {
                int row = rbase + j;
                if (row < N) dp[(size_t)row * 4 + h] = acc[8][j] + cdv;
            }
        }
    }
}

struct Lin3Cfg {
    const float* x; int N; int blocks;
    const bf16x8* wfrag; const float* cd;
    const float* b0; float* o0; float* dA0; float* dB0;
    const float* b1; unsigned short* o1; float* dA1;
    const float* b2; unsigned short* o2; float* dA2;
};

// ---------- merged fused 3-matrix MFMA linear (P and A in one dispatch) ----------
__global__ __launch_bounds__(256) void lin3_mfma_kernel(Lin3Cfg cP, Lin3Cfg cA)
{
    __shared__ short xs_s[64 * 128];
    __shared__ short wl_s[2304 * 8];
    const bool isP = blockIdx.x < (unsigned)cP.blocks;
    const Lin3Cfg& c = isP ? cP : cA;
    const int bx = isP ? blockIdx.x : (blockIdx.x - cP.blocks);
    const int row0 = bx * 64;
    const int N = c.N;

    #pragma unroll
    for (int ii = 0; ii < 4; ++ii) {
        int ci = threadIdx.x + 256 * ii;
        int r = ci >> 4, k8 = ci & 15;
        int srcrow = row0 + r; if (srcrow >= N) srcrow = N - 1;
        const float4* gp = (const float4*)(c.x + (size_t)srcrow * 128 + k8 * 8);
        float4 v0 = gp[0], v1 = gp[1];
        bf16x8 p;
        p[0] = (short)f2bf(v0.x); p[1] = (short)f2bf(v0.y);
        p[2] = (short)f2bf(v0.z); p[3] = (short)f2bf(v0.w);
        p[4] = (short)f2bf(v1.x); p[5] = (short)f2bf(v1.y);
        p[6] = (short)f2bf(v1.z); p[7] = (short)f2bf(v1.w);
        *(bf16x8*)((char*)xs_s + r * 256 + ((k8 * 16) ^ ((r & 7) << 4))) = p;
    }
    #pragma unroll
    for (int ii = 0; ii < 9; ++ii)
        ((bf16x8*)wl_s)[threadIdx.x + 256 * ii] = c.wfrag[threadIdx.x + 256 * ii];
    __syncthreads();
    mfma_compute_store(xs_s, wl_s, row0, N, c.b0, c.o0, nullptr, c.dA0, c.dB0, c.cd);

    __syncthreads();
    #pragma unroll
    for (int ii = 0; ii < 9; ++ii)
        ((bf16x8*)wl_s)[threadIdx.x + 256 * ii] = c.wfrag[2304 + threadIdx.x + 256 * ii];
    __syncthreads();
    mfma_compute_store(xs_s, wl_s, row0, N, c.b1, nullptr, c.o1, c.dA1, nullptr, c.cd + 8);

    __syncthreads();
    #pragma unroll
    for (int ii = 0; ii < 9; ++ii)
        ((bf16x8*)wl_s)[threadIdx.x + 256 * ii] = c.wfrag[2 * 2304 + threadIdx.x + 256 * ii];
    __syncthreads();
    mfma_compute_store(xs_s, wl_s, row0, N, c.b2, nullptr, c.o2, c.dA2, nullptr, c.cd + 16);
}

// ================= bucketed CSR build (buckets of 1024 dsts) =================

// ---- pass A1: per-bucket edge counts (per-wave LDS histograms) ----
__global__ __launch_bounds__(256) void binA_count_kernel(Ptr4i dsts, int* __restrict__ bcnt,
                                                         int nbkMax, int E)
{
    __shared__ int lh[4][128];
    ((int*)lh)[threadIdx.x] = 0;
    ((int*)lh)[threadIdx.x + 256] = 0;
    __syncthreads();
    int r = blockIdx.y;
    int w = threadIdx.x >> 6;
    const int* dst = (r == 0) ? dsts.p0 : (r == 1) ? dsts.p1 : (r == 2) ? dsts.p2 : dsts.p3;
    int base = blockIdx.x * 4096;
    #pragma unroll 4
    for (int ii = 0; ii < 16; ++ii) {
        int i = base + threadIdx.x + 256 * ii;
        if (i < E) atomicAdd(&lh[w][dst[i] >> 10], 1);
    }
    __syncthreads();
    if (threadIdx.x < 128) {
        int v = lh[0][threadIdx.x] + lh[1][threadIdx.x] + lh[2][threadIdx.x] + lh[3][threadIdx.x];
        if (v && threadIdx.x < nbkMax) atomicAdd(&bcnt[r * nbkMax + threadIdx.x], v);
    }
}

// ---- parallel scan of bucket counts (4 relations x 128 lanes, one block) ----
__global__ __launch_bounds__(512) void bin_scan_kernel(const int* __restrict__ bcnt,
                                                       int* __restrict__ bbase,
                                                       int* __restrict__ gwptr, int nbkMax)
{
    __shared__ int sh[4][128];
    int r = threadIdx.x >> 7, b = threadIdx.x & 127;
    int v = (b < nbkMax) ? bcnt[r * nbkMax + b] : 0;
    sh[r][b] = v;
    __syncthreads();
    #pragma unroll
    for (int off = 1; off < 128; off <<= 1) {
        int y = (b >= off) ? sh[r][b - off] : 0;
        __syncthreads();
        sh[r][b] += y;
        __syncthreads();
    }
    if (b < nbkMax) {
        int ex = sh[r][b] - v;
        bbase[r * nbkMax + b] = ex;
        gwptr[r * nbkMax + b] = ex;
    }
}

// ---- pass A2: LDS-binned scatter into bucket-ordered packed array ----
__global__ __launch_bounds__(256) void binA_scatter_kernel(Ptr4i dsts, Ptr4i srcs,
    int* __restrict__ gwptr, unsigned* __restrict__ packed, int nbkMax, int E)
{
    __shared__ int lh[128], loff[128], lptr[128], gb[128];
    __shared__ unsigned stg[4096];
    __shared__ unsigned short sb[4096];
    if (threadIdx.x < 128) lh[threadIdx.x] = 0;
    __syncthreads();
    int r = blockIdx.y;
    const int* dst = (r == 0) ? dsts.p0 : (r == 1) ? dsts.p1 : (r == 2) ? dsts.p2 : dsts.p3;
    const int* src = (r == 0) ? srcs.p0 : (r == 1) ? srcs.p1 : (r == 2) ? srcs.p2 : srcs.p3;
    int base = blockIdx.x * 4096;
    int d16[16], s16[16];
    #pragma unroll 4
    for (int ii = 0; ii < 16; ++ii) {
        int i = base + threadIdx.x + 256 * ii;
        if (i < E) {
            d16[ii] = dst[i];
            s16[ii] = src[i];
            atomicAdd(&lh[d16[ii] >> 10], 1);
        } else d16[ii] = -1;
    }
    __syncthreads();
    if (threadIdx.x == 0) {
        int run = 0;
        for (int b = 0; b < nbkMax; ++b) { loff[b] = run; lptr[b] = run; run += lh[b]; }
    }
    __syncthreads();
    #pragma unroll 4
    for (int ii = 0; ii < 16; ++ii) {
        if (d16[ii] >= 0) {
            int b = d16[ii] >> 10;
            int p = atomicAdd(&lptr[b], 1);
            stg[p] = ((unsigned)s16[ii] << 10) | (unsigned)(d16[ii] & 1023);
            sb[p] = (unsigned short)b;
        }
    }
    __syncthreads();
    if (threadIdx.x < nbkMax && lh[threadIdx.x])
        gb[threadIdx.x] = atomicAdd(&gwptr[r * nbkMax + threadIdx.x], lh[threadIdx.x]);
    __syncthreads();
    int tot = min(4096, E - base);
    #pragma unroll 4
    for (int ii = 0; ii < 16; ++ii) {
        int p = threadIdx.x + 256 * ii;
        if (p < tot) {
            int b = sb[p];
            packed[(size_t)r * E + gb[b] + (p - loff[b])] = stg[p];
        }
    }
}

// ---- pass B: per-bucket CSR finalize ----
__global__ __launch_bounds__(256) void binB_build_kernel(
    const unsigned* __restrict__ packed, const int* __restrict__ bcnt, const int* __restrict__ bbase,
    int nbkMax, int4 Ns, int E, int stride,
    int* __restrict__ start, int* __restrict__ deg, int* __restrict__ csrc)
{
    int r = blockIdx.y, b = blockIdx.x;
    int N = (r == 0) ? Ns.x : (r == 1) ? Ns.y : (r == 2) ? Ns.z : Ns.w;
    int dst0 = b << 10;
    if (dst0 >= N) return;
    int cnt  = bcnt[r * nbkMax + b];
    int base = bbase[r * nbkMax + b];
    __shared__ int hist[1024];
    __shared__ int sums[256];
    #pragma unroll
    for (int i = 0; i < 4; ++i) hist[threadIdx.x * 4 + i] = 0;
    __syncthreads();
    const unsigned* pk = packed + (size_t)r * E + base;
    for (int i = threadIdx.x; i < cnt; i += 256)
        atomicAdd(&hist[pk[i] & 1023], 1);
    __syncthreads();
    int v4[4], s = 0;
    #pragma unroll
    for (int i = 0; i < 4; ++i) { v4[i] = hist[threadIdx.x * 4 + i]; s += v4[i]; }
    sums[threadIdx.x] = s;
    __syncthreads();
    #pragma unroll
    for (int off = 1; off < 256; off <<= 1) {
        int y = (threadIdx.x >= off) ? sums[threadIdx.x - off] : 0;
        __syncthreads();
        sums[threadIdx.x] += y;
        __syncthreads();
    }
    int run = sums[threadIdx.x] - s;
    int* st = start + (size_t)r * stride;
    int* dg = deg   + (size_t)r * stride;
    #pragma unroll
    for (int i = 0; i < 4; ++i) {
        int idx = threadIdx.x * 4 + i;
        int d = dst0 + idx;
        if (d < N) { dg[d] = v4[i]; st[d] = base + run; }
        hist[idx] = run;
        run += v4[i];
    }
    __syncthreads();
    int* cs = csrc + (size_t)r * E + base;
    for (int i = threadIdx.x; i < cnt; i += 256) {
        unsigned e = pk[i];
        int p = atomicAdd(&hist[e & 1023], 1);
        cs[p] = (int)(e >> 10);
    }
}

// ---------- merged per-dst fused GAT: 4 edge slots x 2-deep unroll = 8 gathers in flight ----------
struct GatRel {
    const int* start; const int* deg; const int* csrc;
    const unsigned short* Wh; const float* es; const float* ed;
};
struct GatCfg { float* out; int Nd; int blocks; GatRel rel0, rel1; };

__global__ __launch_bounds__(256) void gat_node_kernel(GatCfg cP, GatCfg cA)
{
    const bool isP = blockIdx.x < (unsigned)cP.blocks;
    const GatCfg& c = isP ? cP : cA;
    const int bx = isP ? blockIdx.x : (blockIdx.x - cP.blocks);
    int gid = bx * 256 + threadIdx.x;
    int d = gid >> 6;
    if (d >= c.Nd) return;
    int lane = threadIdx.x & 63;
    int q = lane >> 4;        // edge slot
    int l = lane & 15;        // dim group: dims 8l..8l+7
    int h = l >> 2;           // head

    const float4* orow = (const float4*)(c.out + (size_t)d * 128);
    float4 A0 = orow[l * 2], A1 = orow[l * 2 + 1];

    #pragma unroll
    for (int rel = 0; rel < 2; ++rel) {
        const GatRel& R = rel ? c.rel1 : c.rel0;
        int st = R.start[d];
        int n  = R.deg[d];
        if (n == 0) continue;
        const uint4* W4 = (const uint4*)R.Wh;   // row = 128 bf16 = 16 uint4
        float edv = R.ed[(size_t)d * 4 + h];
        float sum = 0.f;
        float m0 = 0.f, m1 = 0.f, m2 = 0.f, m3 = 0.f;
        float m4 = 0.f, m5 = 0.f, m6 = 0.f, m7 = 0.f;
        int j = q;
        for (; j + 4 < n; j += 8) {
            int s0 = R.csrc[st + j];
            int s1 = R.csrc[st + j + 4];
            float p0 = __expf(leakyf(R.es[(size_t)s0 * 4 + h] + edv));
            float p1 = __expf(leakyf(R.es[(size_t)s1 * 4 + h] + edv));
            uint4 w0 = W4[(size_t)s0 * 16 + l];
            uint4 w1 = W4[(size_t)s1 * 16 + l];
            sum += p0 + p1;
            m0 += p0 * bflo(w0.x) + p1 * bflo(w1.x);
            m1 += p0 * bfhi(w0.x) + p1 * bfhi(w1.x);
            m2 += p0 * bflo(w0.y) + p1 * bflo(w1.y);
            m3 += p0 * bfhi(w0.y) + p1 * bfhi(w1.y);
            m4 += p0 * bflo(w0.z) + p1 * bflo(w1.z);
            m5 += p0 * bfhi(w0.z) + p1 * bfhi(w1.z);
            m6 += p0 * bflo(w0.w) + p1 * bflo(w1.w);
            m7 += p0 * bfhi(w0.w) + p1 * bfhi(w1.w);
        }
        if (j < n) {
            int s0 = R.csrc[st + j];
            float p0 = __expf(leakyf(R.es[(size_t)s0 * 4 + h] + edv));
            uint4 w0 = W4[(size_t)s0 * 16 + l];
            sum += p0;
            m0 += p0 * bflo(w0.x); m1 += p0 * bfhi(w0.x);
            m2 += p0 * bflo(w0.y); m3 += p0 * bfhi(w0.y);
            m4 += p0 * bflo(w0.z); m5 += p0 * bfhi(w0.z);
            m6 += p0 * bflo(w0.w); m7 += p0 * bfhi(w0.w);
        }
        #pragma unroll
        for (int off = 16; off < 64; off <<= 1) {
            sum += __shfl_xor(sum, off, 64);
            m0 += __shfl_xor(m0, off, 64); m1 += __shfl_xor(m1, off, 64);
            m2 += __shfl_xor(m2, off, 64); m3 += __shfl_xor(m3, off, 64);
            m4 += __shfl_xor(m4, off, 64); m5 += __shfl_xor(m5, off, 64);
            m6 += __shfl_xor(m6, off, 64); m7 += __shfl_xor(m7, off, 64);
        }
        float inv = 1.0f / sum;
        A0.x += m0 * inv; A0.y += m1 * inv; A0.z += m2 * inv; A0.w += m3 * inv;
        A1.x += m4 * inv; A1.y += m5 * inv; A1.z += m6 * inv; A1.w += m7 * inv;
    }
    if (lane < 16) {
        A0.x = fmaxf(A0.x, 0.f); A0.y = fmaxf(A0.y, 0.f);
        A0.z = fmaxf(A0.z, 0.f); A0.w = fmaxf(A0.w, 0.f);
        A1.x = fmaxf(A1.x, 0.f); A1.y = fmaxf(A1.y, 0.f);
        A1.z = fmaxf(A1.z, 0.f); A1.w = fmaxf(A1.w, 0.f);
        float4* ow = (float4*)(c.out + (size_t)d * 128);
        ow[l * 2] = A0; ow[l * 2 + 1] = A1;
    }
}

extern "C" void kernel_launch(void* const* d_in, const int* in_sizes, int n_in,
                              void* d_out, int out_size, void* d_ws, size_t ws_size,
                              hipStream_t stream)
{
    const float* feat_P = (const float*)d_in[0];
    const float* feat_A = (const float*)d_in[1];
    const int* src_p2p = (const int*)d_in[2];
    const int* dst_p2p = (const int*)d_in[3];
    const int* src_p2a = (const int*)d_in[4];
    const int* dst_p2a = (const int*)d_in[5];
    const int* src_a2p = (const int*)d_in[6];
    const int* dst_a2p = (const int*)d_in[7];
    const int* src_a2a = (const int*)d_in[8];
    const int* dst_a2a = (const int*)d_in[9];
    const float* W_P   = (const float*)d_in[10]; const float* b_P   = (const float*)d_in[11];
    const float* W_A   = (const float*)d_in[12]; const float* b_A   = (const float*)d_in[13];
    const float* W_p2p = (const float*)d_in[14]; const float* b_p2p = (const float*)d_in[15];
    const float* W_p2a = (const float*)d_in[16]; const float* b_p2a = (const float*)d_in[17];
    const float* W_a2p = (const float*)d_in[18]; const float* b_a2p = (const float*)d_in[19];
    const float* W_a2a = (const float*)d_in[20]; const float* b_a2a = (const float*)d_in[21];
    const float* att_p2p_src = (const float*)d_in[22];
    const float* att_p2p_dst = (const float*)d_in[23];
    const float* att_p2a_src = (const float*)d_in[24];
    const float* att_p2a_dst = (const float*)d_in[25];
    const float* att_a2p_src = (const float*)d_in[26];
    const float* att_a2p_dst = (const float*)d_in[27];
    const float* att_a2a_src = (const float*)d_in[28];
    const float* att_a2a_dst = (const float*)d_in[29];

    const int NP = in_sizes[0] / 128;
    const int NA = in_sizes[1] / 128;
    const int E  = in_sizes[2];
    const int stride = (NP > NA) ? NP : NA;
    const int nbkMax = (stride + 1023) >> 10;   // <= 128

    float* outP = (float*)d_out;
    float* outA = (float*)d_out + (size_t)NP * 128;

    char* ws = (char*)d_ws;
    size_t off = 0;
    auto alloc = [&](size_t bytes) -> void* {
        void* p = ws + off;
        off += (bytes + 255) & ~(size_t)255;
        return p;
    };
    unsigned short* Whp2p = (unsigned short*)alloc((size_t)NP * 128 * 2);
    unsigned short* Whp2a = (unsigned short*)alloc((size_t)NP * 128 * 2);
    unsigned short* Wha2p = (unsigned short*)alloc((size_t)NA * 128 * 2);
    unsigned short* Wha2a = (unsigned short*)alloc((size_t)NA * 128 * 2);
    float* es_p2p = (float*)alloc((size_t)NP * 16);
    float* es_p2a = (float*)alloc((size_t)NP * 16);
    float* es_a2p = (float*)alloc((size_t)NA * 16);
    float* es_a2a = (float*)alloc((size_t)NA * 16);
    float* ed_p2p = (float*)alloc((size_t)NP * 16);
    float* ed_a2p = (float*)alloc((size_t)NP * 16);
    float* ed_p2a = (float*)alloc((size_t)NA * 16);
    float* ed_a2a = (float*)alloc((size_t)NA * 16);
    int* deg    = (int*)alloc((size_t)4 * stride * 4);
    int* start  = (int*)alloc((size_t)4 * stride * 4);
    int* csrc   = (int*)alloc((size_t)4 * E * 4);
    unsigned* packed = (unsigned*)alloc((size_t)4 * E * 4);
    int* bcnt   = (int*)alloc((size_t)4 * nbkMax * 4);
    int* bbase  = (int*)alloc((size_t)4 * nbkMax * 4);
    int* gwptr  = (int*)alloc((size_t)4 * nbkMax * 4);
    bf16x8* wfrag = (bf16x8*)alloc((size_t)6 * 2304 * 16);
    float* cd     = (float*)alloc((size_t)6 * 8 * 4);

    // relation order: 0=p2p(dst P), 1=a2p(dst P), 2=p2a(dst A), 3=a2a(dst A)
    Ptr4i dsts = {dst_p2p, dst_a2p, dst_p2a, dst_a2a};
    Ptr4i srcs = {src_p2p, src_a2p, src_p2a, src_a2a};
    int4 Ns = make_int4(NP, NP, NA, NA);

    // ---- 0) prep weights (+ zero bcnt) ----
    {
        PrepM m0 = {W_P,   b_P,   att_p2p_dst, att_a2p_dst};
        PrepM m1 = {W_p2p, b_p2p, att_p2p_src, nullptr};
        PrepM m2 = {W_p2a, b_p2a, att_p2a_src, nullptr};
        PrepM m3 = {W_A,   b_A,   att_p2a_dst, att_a2a_dst};
        PrepM m4 = {W_a2p, b_a2p, att_a2p_src, nullptr};
        PrepM m5 = {W_a2a, b_a2a, att_a2a_src, nullptr};
        prep_kernel<<<dim3(6, 4), 256, 0, stream>>>(m0, m1, m2, m3, m4, m5, wfrag, cd,
                                                    bcnt, 4 * nbkMax);
    }

    // ---- 1) merged MFMA linears ----
    {
        Lin3Cfg cP = {feat_P, NP, (NP + 63) / 64, wfrag, cd,
                      b_P, outP, ed_p2p, ed_a2p,
                      b_p2p, Whp2p, es_p2p,
                      b_p2a, Whp2a, es_p2a};
        Lin3Cfg cA = {feat_A, NA, (NA + 63) / 64, wfrag + (size_t)3 * 2304, cd + 24,
                      b_A, outA, ed_p2a, ed_a2a,
                      b_a2p, Wha2p, es_a2p,
                      b_a2a, Wha2a, es_a2a};
        lin3_mfma_kernel<<<cP.blocks + cA.blocks, 256, 0, stream>>>(cP, cA);
    }

    // ---- 2) bucketed CSR build ----
    {
        dim3 gA((E + 4095) / 4096, 4);
        binA_count_kernel<<<gA, 256, 0, stream>>>(dsts, bcnt, nbkMax, E);
        bin_scan_kernel<<<1, 512, 0, stream>>>(bcnt, bbase, gwptr, nbkMax);
        binA_scatter_kernel<<<gA, 256, 0, stream>>>(dsts, srcs, gwptr, packed, nbkMax, E);
        binB_build_kernel<<<dim3(nbkMax, 4), 256, 0, stream>>>(packed, bcnt, bbase,
            nbkMax, Ns, E, stride, start, deg, csrc);
    }

    // ---- 3) merged per-dst aggregation (+self +relu) ----
    {
        GatCfg cP = {outP, NP, (NP * 64 + 255) / 256,
            {start + 0 * (size_t)stride, deg + 0 * (size_t)stride, csrc + 0 * (size_t)E, Whp2p, es_p2p, ed_p2p},
            {start + 1 * (size_t)stride, deg + 1 * (size_t)stride, csrc + 1 * (size_t)E, Wha2p, es_a2p, ed_a2p}};
        GatCfg cA = {outA, NA, (NA * 64 + 255) / 256,
            {start + 2 * (size_t)stride, deg + 2 * (size_t)stride, csrc + 2 * (size_t)E, Whp2a, es_p2a, ed_p2a},
            {start + 3 * (size_t)stride, deg + 3 * (size_t)stride, csrc + 3 * (size_t)E, Wha2a, es_a2a, ed_a2a}};
        gat_node_kernel<<<cP.blocks + cA.blocks, 256, 0, stream>>>(cP, cA);
    }
}